// Round 17
// baseline (317.474 us; speedup 1.0000x reference)
//
#include <hip/hip_runtime.h>
#include <hip/hip_bf16.h>
#include <math.h>

#define N_NODES 100000
#define N_EDGES 1600000
#define F_IN 100
#define H 64
#define C 18
#define BSHIFT 8
#define BSIZE 256
#define NBUCKETS ((N_NODES + BSIZE - 1) >> BSHIFT)   // 391
#define NBLK 256
#define CHUNK (N_EDGES / NBLK)                       // 6250

typedef __attribute__((ext_vector_type(8))) short v8s;   // 8 bf16 (4 VGPRs)
typedef __attribute__((ext_vector_type(4))) float v4f;   // 4 f32 acc
typedef __attribute__((ext_vector_type(2))) float v2f;

// ----------------- bf16x2 / fp8x2 pack/unpack -----------------

__device__ __forceinline__ unsigned bf16_rne(float f) {
    unsigned u = __float_as_uint(f);
    return (u + 0x7FFFu + ((u >> 16) & 1u)) >> 16;
}
__device__ __forceinline__ unsigned pack_bf2(float a, float b) {
    return bf16_rne(a) | (bf16_rne(b) << 16);
}
__device__ __forceinline__ float2 unpack_bf2(unsigned u) {
    return make_float2(__uint_as_float(u << 16), __uint_as_float(u & 0xFFFF0000u));
}
// OCP e4m3 pair in a ushort: byte0 = a (stack0), byte1 = b (stack1). HW converts.
__device__ __forceinline__ ushort pack_fp8x2(float a, float b) {
    int r = __builtin_amdgcn_cvt_pk_fp8_f32(a, b, 0, false);
    return (ushort)(r & 0xFFFF);
}
__device__ __forceinline__ float2 unpack_fp8x2(ushort u) {
    v2f r = __builtin_amdgcn_cvt_pk_f32_fp8((int)u, false);
    return make_float2(r[0], r[1]);
}

// ----------------- scan helpers (for histx only) -----------------

__global__ void scan1_kernel(const int* __restrict__ cnt, int* __restrict__ excl,
                             int* __restrict__ bsum, int n) {
    __shared__ int tmp[256];
    int t = threadIdx.x;
    int i = blockIdx.x * 256 + t;
    int v = (i < n) ? cnt[i] : 0;
    tmp[t] = v;
    __syncthreads();
    for (int off = 1; off < 256; off <<= 1) {
        int xv = (t >= off) ? tmp[t - off] : 0;
        __syncthreads();
        tmp[t] += xv;
        __syncthreads();
    }
    if (i < n) excl[i] = tmp[t] - v;
    if (t == 255) bsum[blockIdx.x] = tmp[255];
}

// block 0: parallel exclusive scan of bsum[0..nb). blocks 1..: weight prep.
__global__ void __launch_bounds__(512) scan2p_prep_kernel(
        int* __restrict__ bsum, int nb,
        const float* __restrict__ iw1, const float* __restrict__ rw1,
        const float* __restrict__ w1,  const float* __restrict__ iw2,
        const float* __restrict__ rw2, const float* __restrict__ w2,
        ushort* __restrict__ W1T, ushort* __restrict__ WmT,
        ushort* __restrict__ W2T, ushort* __restrict__ W3T) {
    int t = threadIdx.x;
    if (blockIdx.x == 0) {
        __shared__ int s[512];
        int v = (t < nb) ? bsum[t] : 0;
        s[t] = v;
        __syncthreads();
        for (int off = 1; off < 512; off <<= 1) {
            int xv = (t >= off) ? s[t - off] : 0;
            __syncthreads();
            s[t] += xv;
            __syncthreads();
        }
        if (t < nb) bsum[t] = s[t] - v;   // exclusive
        return;
    }
    int gid = (blockIdx.x - 1) * 512 + t;
    if (gid < 32768) {                         // W1T: 4*64*128
        int idx = gid;
        int m = idx >> 13, nn = (idx >> 7) & 63, kk = idx & 127;
        int stk = m & 1, isWr = m >> 1;
        float v = 0.f;
        if (kk < F_IN) v = (isWr ? rw1 : iw1)[((size_t)stk * F_IN + kk) * 64 + nn];
        W1T[idx] = (ushort)bf16_rne(v);
    } else if (gid < 32768 + 8192) {           // WmT: 2*64*64
        int idx = gid - 32768;
        int stk = idx >> 12, g = (idx >> 6) & 63, f = idx & 63;
        WmT[idx] = (ushort)bf16_rne(w1[((size_t)stk * 64 + f) * 64 + g]);
    } else if (gid < 32768 + 8192 + 8192) {    // W2T: 4*32*64
        int idx = gid - 32768 - 8192;
        int m = idx >> 11, col = (idx >> 6) & 31, k = idx & 63;
        int stk = m & 1, isWr = m >> 1;
        float v = 0.f;
        if (col < C) v = (isWr ? rw2 : iw2)[((size_t)stk * H + k) * C + col];
        W2T[idx] = (ushort)bf16_rne(v);
    } else if (gid < 32768 + 8192 + 8192 + 2048) {  // W3T: 2*32*32
        int idx = gid - 32768 - 8192 - 8192;
        int stk = idx >> 10, col = (idx >> 5) & 31, k = idx & 31;
        float v = 0.f;
        if (col < C && k < C) v = w2[((size_t)stk * C + k) * C + col];
        W3T[idx] = (ushort)bf16_rne(v);
    }
}

__global__ void scan3_kernel(int* __restrict__ arr, const int* __restrict__ bsum,
                             int n, int sent) {
    int i = blockIdx.x * 256 + threadIdx.x;
    if (i < n) arr[i] += bsum[i >> 8];
    if (i == n && sent >= 0) arr[n] = sent;
}

// ----------------- bucket sort (no global atomics anywhere) -----------------

__global__ void __launch_bounds__(256) histA_kernel(const int* __restrict__ tgt,
                                                    int* __restrict__ hist) {
    __shared__ int h[NBUCKETS];
    int blk = blockIdx.x, t = threadIdx.x;
    for (int i = t; i < NBUCKETS; i += 256) h[i] = 0;
    __syncthreads();
    int e0 = blk * CHUNK, e1 = e0 + CHUNK;
    for (int e = e0 + t; e < e1; e += 256) atomicAdd(&h[tgt[e] >> BSHIFT], 1);
    __syncthreads();
    for (int i = t; i < NBUCKETS; i += 256) hist[i * NBLK + blk] = h[i];
}

// packed word = src | (t_local << 17)   (src < 2^17, t_local < 256)
__global__ void __launch_bounds__(256) scatterC_kernel(
        const int* __restrict__ src, const int* __restrict__ tgt,
        const int* __restrict__ histx, unsigned* __restrict__ tmp) {
    __shared__ int cur[NBUCKETS];
    int blk = blockIdx.x, t = threadIdx.x;
    for (int i = t; i < NBUCKETS; i += 256) cur[i] = histx[i * NBLK + blk];
    __syncthreads();
    int e0 = blk * CHUNK, e1 = e0 + CHUNK;
    for (int e = e0 + t; e < e1; e += 256) {
        int s = src[e], tg = tgt[e];
        int b = tg >> BSHIFT;
        int pos = atomicAdd(&cur[b], 1);
        tmp[pos] = (unsigned)s | ((unsigned)(tg & (BSIZE - 1)) << 17);
    }
}

// one block per bucket: LDS hist of t_local -> degree; LDS scan -> rp; node-sorted ssrc.
__global__ void __launch_bounds__(256) bucketD2_kernel(
        const unsigned* __restrict__ tmp, const int* __restrict__ histx,
        int* __restrict__ rp, float* __restrict__ dinv, int* __restrict__ ssrc) {
    __shared__ int cnt_l[BSIZE];
    __shared__ int scan_l[BSIZE];
    int b = blockIdx.x;
    int t = threadIdx.x;
    int e_lo = histx[(size_t)b * NBLK];
    int e_hi = (b + 1 < NBUCKETS) ? histx[(size_t)(b + 1) * NBLK] : N_EDGES;
    int n_lo = b << BSHIFT;
    int n_hi = min(n_lo + BSIZE, N_NODES);
    int nn = n_hi - n_lo;
    cnt_l[t] = 0;
    __syncthreads();
    for (int e = e_lo + t; e < e_hi; e += 256)
        atomicAdd(&cnt_l[(int)(tmp[e] >> 17)], 1);
    __syncthreads();
    int v = cnt_l[t];
    scan_l[t] = v;
    __syncthreads();
    for (int off = 1; off < 256; off <<= 1) {
        int xv = (t >= off) ? scan_l[t - off] : 0;
        __syncthreads();
        scan_l[t] += xv;
        __syncthreads();
    }
    int my_start = e_lo + scan_l[t] - v;
    if (t < nn) {
        rp[n_lo + t] = my_start;
        dinv[n_lo + t] = (v > 0) ? rsqrtf((float)v) : 0.f;
    }
    if (b == NBUCKETS - 1 && t == 0) rp[N_NODES] = N_EDGES;
    __syncthreads();
    cnt_l[t] = my_start;
    __syncthreads();
    for (int e = e_lo + t; e < e_hi; e += 256) {
        unsigned p = tmp[e];
        int s = (int)(p & 0x1FFFFu);
        int tl = (int)(p >> 17);
        int pos = atomicAdd(&cnt_l[tl], 1);
        ssrc[pos] = s;
    }
}

// ----------------- MFMA fragment conventions -----------------
// A-frag (16x16x32): lane(q=lane>>4, cl=lane&15) holds A[row=cl][k=q*8+j].
// B-frag: lane holds B[k=q*8+j][col=cl] -> weights stored [col][k], 16B/lane.
// C/D: col=lane&15, row=q*4+reg (m89-verified).
// LDS A-tiles: granule(16B) index XOR'd with row bits to kill bank conflicts.

// dense1: 32-node tiles (grid 3125), float4 x loads, bf16-convert in staging.
// g output: fp8x2 (stack0,stack1) per (node,col); root: bf16x2.
__global__ void __launch_bounds__(256) dense1_mfma(
        const float* __restrict__ x, const ushort* __restrict__ W1T,
        const float* __restrict__ dinv,
        ushort* __restrict__ g, unsigned* __restrict__ root) {
    __shared__ char xs[32 * 256];   // 8KB: 32 rows x 128 bf16 (K pad), swizzled
    int tid = threadIdx.x;
    int b0 = blockIdx.x * 32;
    // stage: 32 rows x 25 float4 (row bases 16B-aligned: 400 = 25*16)
    for (int i = tid; i < 32 * 25; i += 256) {
        int row = i / 25, f4 = i - row * 25;
        int grow = b0 + row;
        float4 v = make_float4(0.f, 0.f, 0.f, 0.f);
        if (grow < N_NODES) v = *(const float4*)(x + (size_t)grow * F_IN + f4 * 4);
        unsigned p0 = pack_bf2(v.x, v.y);
        unsigned p1 = pack_bf2(v.z, v.w);
        int pr = f4 * 2;                       // u32-pair index; pr and pr+1 share a granule
        int gr = (pr >> 2) ^ (row & 7);
        char* base = xs + row * 256 + (gr << 4) + (pr & 3) * 4;
        *(unsigned*)base = p0;
        *(unsigned*)(base + 4) = p1;
    }
    // zero-pad K cols 100..127 (u32 pairs 50..63)
    for (int i = tid; i < 32 * 14; i += 256) {
        int row = i / 14, pr = 50 + (i - row * 14);
        int gr = (pr >> 2) ^ (row & 7);
        *(unsigned*)(xs + row * 256 + (gr << 4) + (pr & 3) * 4) = 0;
    }
    __syncthreads();
    int lane = tid & 63;
    int w = __builtin_amdgcn_readfirstlane(tid >> 6);
    int q = lane >> 4, cl = lane & 15;
    int isWr = w >> 1;
    int colbase = (w & 1) * 32;
    v8s bfr[2][2][4];   // [stk][ntile][kstep]
    #pragma unroll
    for (int stk = 0; stk < 2; ++stk)
        #pragma unroll
        for (int nt = 0; nt < 2; ++nt)
            #pragma unroll
            for (int ks = 0; ks < 4; ++ks) {
                const ushort* p = W1T + ((size_t)(isWr * 2 + stk) * 64 + colbase + nt * 16 + cl) * 128
                                  + ks * 32 + q * 8;
                bfr[stk][nt][ks] = *(const v8s*)p;
            }
    #pragma unroll
    for (int mt = 0; mt < 2; ++mt) {
        v8s afr[4];
        #pragma unroll
        for (int ks = 0; ks < 4; ++ks) {
            int row = mt * 16 + cl;
            int gr = (ks * 4 + q) ^ (row & 7);
            afr[ks] = *(const v8s*)(xs + row * 256 + (gr << 4));
        }
        v4f acc[2][2];
        #pragma unroll
        for (int stk = 0; stk < 2; ++stk)
            #pragma unroll
            for (int nt = 0; nt < 2; ++nt) {
                v4f a = {0.f, 0.f, 0.f, 0.f};
                #pragma unroll
                for (int ks = 0; ks < 4; ++ks)
                    a = __builtin_amdgcn_mfma_f32_16x16x32_bf16(afr[ks], bfr[stk][nt][ks], a, 0, 0, 0);
                acc[stk][nt] = a;
            }
        #pragma unroll
        for (int nt = 0; nt < 2; ++nt)
            #pragma unroll
            for (int reg = 0; reg < 4; ++reg) {
                int node = b0 + mt * 16 + q * 4 + reg;
                if (node < N_NODES) {
                    int col = colbase + nt * 16 + cl;
                    if (isWr == 0) {
                        float dv = dinv[node];
                        g[(size_t)node * 64 + col] = pack_fp8x2(dv * acc[0][nt][reg], dv * acc[1][nt][reg]);
                    } else {
                        root[(size_t)node * 64 + col] = pack_bf2(acc[0][nt][reg], acc[1][nt][reg]);
                    }
                }
            }
    }
}

// dense_mid: hk0/hk1 planar bf16 -> fp8x2 g2 (x dinv). block = 64 nodes.
__global__ void __launch_bounds__(256) dense_mid_mfma(
        const ushort* __restrict__ hk0, const ushort* __restrict__ hk1,
        const ushort* __restrict__ WmT, const float* __restrict__ dinv,
        ushort* __restrict__ g2) {
    __shared__ char hs[2 * 64 * 128];   // 16KB: [stk][row][64 bf16], swizzled
    int tid = threadIdx.x;
    int b0 = blockIdx.x * 64;
    for (int i = tid; i < 1024; i += 256) {          // 2 tiles * 64 rows * 8 granules
        int stk = i >> 9, rem = i & 511, row = rem >> 3, gr = rem & 7;
        int grow = b0 + row;
        uint4 v = make_uint4(0, 0, 0, 0);
        const ushort* srcp = stk ? hk1 : hk0;
        if (grow < N_NODES) v = *(const uint4*)(srcp + (size_t)grow * 64 + gr * 8);
        *(uint4*)(hs + stk * 8192 + row * 128 + ((gr ^ (row & 7)) << 4)) = v;
    }
    __syncthreads();
    int lane = tid & 63;
    int w = __builtin_amdgcn_readfirstlane(tid >> 6);
    int q = lane >> 4, cl = lane & 15;
    v8s bfr[2][2];   // [stk][kstep]
    #pragma unroll
    for (int stk = 0; stk < 2; ++stk)
        #pragma unroll
        for (int ks = 0; ks < 2; ++ks)
            bfr[stk][ks] = *(const v8s*)(WmT + ((size_t)stk * 64 + w * 16 + cl) * 64 + ks * 32 + q * 8);
    #pragma unroll
    for (int mt = 0; mt < 4; ++mt) {
        v4f acc[2];
        #pragma unroll
        for (int stk = 0; stk < 2; ++stk) {
            v4f a = {0.f, 0.f, 0.f, 0.f};
            #pragma unroll
            for (int ks = 0; ks < 2; ++ks) {
                int row = mt * 16 + cl;
                int gr = (ks * 4 + q) ^ (row & 7);
                v8s af = *(const v8s*)(hs + stk * 8192 + row * 128 + (gr << 4));
                a = __builtin_amdgcn_mfma_f32_16x16x32_bf16(af, bfr[stk][ks], a, 0, 0, 0);
            }
            acc[stk] = a;
        }
        #pragma unroll
        for (int reg = 0; reg < 4; ++reg) {
            int node = b0 + mt * 16 + q * 4 + reg;
            if (node < N_NODES) {
                float dv = dinv[node];
                g2[(size_t)node * 64 + w * 16 + cl] = pack_fp8x2(dv * acc[0][reg], dv * acc[1][reg]);
            }
        }
    }
}

// dense_y2: yb planar bf16 -> h2 fp8x2 (x dinv) / root2 bf16x2. block = 64 nodes.
__global__ void __launch_bounds__(256) dense_y2_mfma(
        const ushort* __restrict__ yb, const ushort* __restrict__ W2T,
        const float* __restrict__ dinv,
        ushort* __restrict__ h2, unsigned* __restrict__ root2) {
    __shared__ char ys[64 * 128];   // 8KB: 64 rows x 64 bf16, swizzled
    int tid = threadIdx.x;
    int b0 = blockIdx.x * 64;
    for (int i = tid; i < 512; i += 256) {           // 64 rows * 8 granules
        int row = i >> 3, gr = i & 7;
        int grow = b0 + row;
        uint4 v = make_uint4(0, 0, 0, 0);
        if (grow < N_NODES) v = *(const uint4*)(yb + (size_t)grow * 64 + gr * 8);
        *(uint4*)(ys + row * 128 + ((gr ^ (row & 7)) << 4)) = v;
    }
    __syncthreads();
    int lane = tid & 63;
    int w = __builtin_amdgcn_readfirstlane(tid >> 6);
    int q = lane >> 4, cl = lane & 15;
    int isWr = w >> 1;
    int mbase = (w & 1) * 2;
    v8s bfr[2][2][2];   // [stk][ntile][kstep]
    #pragma unroll
    for (int stk = 0; stk < 2; ++stk)
        #pragma unroll
        for (int nt = 0; nt < 2; ++nt)
            #pragma unroll
            for (int ks = 0; ks < 2; ++ks)
                bfr[stk][nt][ks] = *(const v8s*)(W2T + ((size_t)(isWr * 2 + stk) * 32 + nt * 16 + cl) * 64
                                                 + ks * 32 + q * 8);
    #pragma unroll
    for (int mi = 0; mi < 2; ++mi) {
        int mt = mbase + mi;
        v8s afr[2];
        #pragma unroll
        for (int ks = 0; ks < 2; ++ks) {
            int row = mt * 16 + cl;
            int gr = (ks * 4 + q) ^ (row & 7);
            afr[ks] = *(const v8s*)(ys + row * 128 + (gr << 4));
        }
        v4f acc[2][2];
        #pragma unroll
        for (int stk = 0; stk < 2; ++stk)
            #pragma unroll
            for (int nt = 0; nt < 2; ++nt) {
                v4f a = {0.f, 0.f, 0.f, 0.f};
                #pragma unroll
                for (int ks = 0; ks < 2; ++ks)
                    a = __builtin_amdgcn_mfma_f32_16x16x32_bf16(afr[ks], bfr[stk][nt][ks], a, 0, 0, 0);
                acc[stk][nt] = a;
            }
        #pragma unroll
        for (int nt = 0; nt < 2; ++nt)
            #pragma unroll
            for (int reg = 0; reg < 4; ++reg) {
                int node = b0 + mt * 16 + q * 4 + reg;
                int col = nt * 16 + cl;
                if (node < N_NODES && col < C) {
                    if (isWr == 0) {
                        float dv = dinv[node];
                        h2[(size_t)node * C + col] = pack_fp8x2(dv * acc[0][nt][reg], dv * acc[1][nt][reg]);
                    } else {
                        root2[(size_t)node * C + col] = pack_bf2(acc[0][nt][reg], acc[1][nt][reg]);
                    }
                }
            }
    }
}

// dense_last: p18k0/p18k1 planar bf16 -> h3 fp8x2 (x dinv). block = 64 nodes.
__global__ void __launch_bounds__(256) dense_last_mfma(
        const ushort* __restrict__ ok0, const ushort* __restrict__ ok1,
        const ushort* __restrict__ W3T, const float* __restrict__ dinv,
        ushort* __restrict__ h3) {
    __shared__ char hs[2 * 64 * 64];   // 8KB: [stk][row][32 bf16], swizzle gr^(row&3)
    int tid = threadIdx.x;
    int b0 = blockIdx.x * 64;
    for (int i = tid; i < 2048; i += 256) ((unsigned*)hs)[i] = 0;
    __syncthreads();
    for (int i = tid; i < 4096; i += 256) {          // 2 stk * 64 rows * 32 cols
        int stk = i >> 11, row = (i >> 5) & 63, col = i & 31;
        int node = b0 + row;
        if (col < C && node < N_NODES) {
            ushort v = (stk ? ok1 : ok0)[(size_t)node * C + col];
            int gr = (col >> 3) ^ (row & 3);
            *(ushort*)(hs + stk * 4096 + row * 64 + (gr << 4) + (col & 7) * 2) = v;
        }
    }
    __syncthreads();
    int lane = tid & 63;
    int w = __builtin_amdgcn_readfirstlane(tid >> 6);
    int q = lane >> 4, cl = lane & 15;
    v8s bfr[2][2];   // [stk][ntile]
    #pragma unroll
    for (int stk = 0; stk < 2; ++stk)
        #pragma unroll
        for (int nt = 0; nt < 2; ++nt)
            bfr[stk][nt] = *(const v8s*)(W3T + ((size_t)stk * 32 + nt * 16 + cl) * 32 + q * 8);
    int row = w * 16 + cl;
    int gr = q ^ (row & 3);
    v8s af0 = *(const v8s*)(hs + row * 64 + (gr << 4));
    v8s af1 = *(const v8s*)(hs + 4096 + row * 64 + (gr << 4));
    v4f acc[2][2];
    #pragma unroll
    for (int nt = 0; nt < 2; ++nt) {
        acc[0][nt] = __builtin_amdgcn_mfma_f32_16x16x32_bf16(af0, bfr[0][nt], (v4f){0.f,0.f,0.f,0.f}, 0, 0, 0);
        acc[1][nt] = __builtin_amdgcn_mfma_f32_16x16x32_bf16(af1, bfr[1][nt], (v4f){0.f,0.f,0.f,0.f}, 0, 0, 0);
    }
    #pragma unroll
    for (int nt = 0; nt < 2; ++nt)
        #pragma unroll
        for (int reg = 0; reg < 4; ++reg) {
            int node = b0 + w * 16 + q * 4 + reg;
            int col = nt * 16 + cl;
            if (node < N_NODES && col < C) {
                float dv = dinv[node];
                h3[(size_t)node * C + col] = pack_fp8x2(dv * acc[0][nt][reg], dv * acc[1][nt][reg]);
            }
        }
}

// ----------------- propagation -----------------

// prop64: wave per node, 64 lanes = 64 cols, fp8x2 table, unroll-8.
template <int FINAL>
__global__ void __launch_bounds__(256) prop64_kernel(
        const ushort* __restrict__ g, const unsigned* __restrict__ root,
        const float* __restrict__ b, const float* __restrict__ dinv,
        const int* __restrict__ rp, const int* __restrict__ ssrc,
        ushort* __restrict__ ok0, ushort* __restrict__ ok1, ushort* __restrict__ yb) {
    int lane = threadIdx.x & 63;
    int wid = __builtin_amdgcn_readfirstlane((int)((blockIdx.x * 256 + threadIdx.x) >> 6));
    if (wid >= N_NODES) return;
    int e0 = rp[wid], e1 = rp[wid + 1];
    float a0 = 0.f, a1 = 0.f;
    int e = e0;
    for (; e + 8 <= e1; e += 8) {
        ushort u[8];
        #pragma unroll
        for (int j = 0; j < 8; ++j) u[j] = g[(size_t)ssrc[e + j] * H + lane];
        #pragma unroll
        for (int j = 0; j < 8; ++j) { float2 v = unpack_fp8x2(u[j]); a0 += v.x; a1 += v.y; }
    }
    for (; e < e1; ++e) {
        float2 v = unpack_fp8x2(g[(size_t)ssrc[e] * H + lane]);
        a0 += v.x; a1 += v.y;
    }
    float dv = dinv[wid];
    float2 rt = unpack_bf2(root[(size_t)wid * H + lane]);
    float o0 = fmaxf(fmaf(dv, a0, rt.x + b[lane]), 0.f);
    float o1 = fmaxf(fmaf(dv, a1, rt.y + b[H + lane]), 0.f);
    if (FINAL) {
        yb[(size_t)wid * H + lane] = (ushort)bf16_rne(0.5f * (o0 + o1));
    } else {
        ok0[(size_t)wid * H + lane] = (ushort)bf16_rne(o0);
        ok1[(size_t)wid * H + lane] = (ushort)bf16_rne(o1);
    }
}

// prop18: wave per node; each gather instruction loads TWO edges' rows
// (lane half selects between two SCALAR src indices -> e stays wave-uniform,
// ssrc stays on the s_load path). Combine halves via shfl_xor(32).
template <int FINAL>
__global__ void __launch_bounds__(256) prop18_kernel(
        const ushort* __restrict__ g, const unsigned* __restrict__ root,
        const float* __restrict__ b, const float* __restrict__ dinv,
        const int* __restrict__ rp, const int* __restrict__ ssrc,
        ushort* __restrict__ ok0, ushort* __restrict__ ok1, float* __restrict__ outp) {
    int lane = threadIdx.x & 63;
    int wid = __builtin_amdgcn_readfirstlane((int)((blockIdx.x * 256 + threadIdx.x) >> 6));
    if (wid >= N_NODES) return;
    int e0 = rp[wid], e1 = rp[wid + 1];
    bool hi = lane >= 32;
    int c32 = lane & 31;
    bool actG = c32 < C;
    int c = actG ? c32 : 0;
    float a0 = 0.f, a1 = 0.f;
    int e = e0;
    for (; e + 16 <= e1; e += 16) {   // 8 instructions x 2 edges each
        ushort u[8];
        #pragma unroll
        for (int j = 0; j < 8; ++j) {
            int s0 = ssrc[e + 2 * j];        // scalar (e uniform)
            int s1 = ssrc[e + 2 * j + 1];    // scalar
            int srow = hi ? s1 : s0;
            u[j] = g[(size_t)srow * C + c];
        }
        if (actG) {
            #pragma unroll
            for (int j = 0; j < 8; ++j) { float2 v = unpack_fp8x2(u[j]); a0 += v.x; a1 += v.y; }
        }
    }
    for (; e + 2 <= e1; e += 2) {
        int s0 = ssrc[e];
        int s1 = ssrc[e + 1];
        int srow = hi ? s1 : s0;
        float2 v = unpack_fp8x2(g[(size_t)srow * C + c]);
        if (actG) { a0 += v.x; a1 += v.y; }
    }
    if (e < e1) {   // odd last edge: half 0 only
        int s0 = ssrc[e];
        float2 v = unpack_fp8x2(g[(size_t)s0 * C + c]);
        if (actG && !hi) { a0 += v.x; a1 += v.y; }
    }
    a0 += __shfl_xor(a0, 32, 64);
    a1 += __shfl_xor(a1, 32, 64);
    float dv = dinv[wid];
    bool actO = lane < C;
    if (!FINAL) {
        if (actO) {
            float2 rt = unpack_bf2(root[(size_t)wid * C + c]);
            float o0 = fmaxf(fmaf(dv, a0, rt.x + b[c]), 0.f);
            float o1 = fmaxf(fmaf(dv, a1, rt.y + b[C + c]), 0.f);
            ok0[(size_t)wid * C + c] = (ushort)bf16_rne(o0);
            ok1[(size_t)wid * C + c] = (ushort)bf16_rne(o1);
        }
    } else {
        float m = -INFINITY;
        if (actO) {
            float2 rt = unpack_bf2(root[(size_t)wid * C + c]);
            float o0 = fmaxf(fmaf(dv, a0, rt.x + b[c]), 0.f);
            float o1 = fmaxf(fmaf(dv, a1, rt.y + b[C + c]), 0.f);
            m = 0.5f * (o0 + o1);
        }
        float mx = m;
        #pragma unroll
        for (int off = 16; off >= 1; off >>= 1) mx = fmaxf(mx, __shfl_xor(mx, off, 64));
        float ex = actO ? __expf(m - mx) : 0.f;
        float sum = ex;
        #pragma unroll
        for (int off = 16; off >= 1; off >>= 1) sum += __shfl_xor(sum, off, 64);
        if (actO) outp[(size_t)wid * C + c] = m - mx - logf(sum);
    }
}

// ----------------- launch -----------------

extern "C" void kernel_launch(void* const* d_in, const int* in_sizes, int n_in,
                              void* d_out, int out_size, void* d_ws, size_t ws_size,
                              hipStream_t stream) {
    const float* x        = (const float*)d_in[0];
    const int*   ei       = (const int*)d_in[1];
    const float* init_w1  = (const float*)d_in[2];
    const float* w1       = (const float*)d_in[3];
    const float* root_w1  = (const float*)d_in[4];
    const float* b1       = (const float*)d_in[5];
    const float* init_w2  = (const float*)d_in[6];
    const float* w2       = (const float*)d_in[7];
    const float* root_w2  = (const float*)d_in[8];
    const float* b2       = (const float*)d_in[9];
    const int* src = ei;
    const int* tgt = ei + N_EDGES;
    float* out = (float*)d_out;

    char* w = (char*)d_ws;
    size_t off = 0;
    auto alloc = [&](size_t bytes) -> char* {
        char* p = w + off;
        off += (bytes + 255) & ~(size_t)255;
        return p;
    };
    int*      rp    = (int*)alloc((size_t)(N_NODES + 1) * 4);
    float*    dinv  = (float*)alloc((size_t)N_NODES * 4);
    int*      bsum  = (int*)alloc(512 * 4);
    int*      hist  = (int*)alloc((size_t)NBUCKETS * NBLK * 4);
    int*      histx = (int*)alloc((size_t)NBUCKETS * NBLK * 4);
    unsigned* tmp   = (unsigned*)alloc((size_t)N_EDGES * 4);
    int*      ssrc  = (int*)alloc((size_t)N_EDGES * 4);
    ushort*   W1T   = (ushort*)alloc((size_t)4 * 64 * 128 * 2);
    ushort*   WmT   = (ushort*)alloc((size_t)2 * 64 * 64 * 2);
    ushort*   W2T   = (ushort*)alloc((size_t)4 * 32 * 64 * 2);
    ushort*   W3T   = (ushort*)alloc((size_t)2 * 32 * 32 * 2);
    ushort*   g1    = (ushort*)alloc((size_t)N_NODES * H * 2);    // 12.8 MB (fp8x2)
    unsigned* root1 = (unsigned*)alloc((size_t)N_NODES * H * 4);  // 25.6 MB
    ushort*   hk0   = (ushort*)alloc((size_t)N_NODES * H * 2);    // 12.8 MB
    ushort*   hk1   = (ushort*)alloc((size_t)N_NODES * H * 2);    // 12.8 MB
    ushort*   g2    = (ushort*)alloc((size_t)N_NODES * H * 2);    // 12.8 MB (fp8x2)
    ushort*   yb    = (ushort*)alloc((size_t)N_NODES * H * 2);    // 12.8 MB
    ushort*   h2u   = (ushort*)alloc((size_t)N_NODES * C * 2);    // 3.6 MB (fp8x2)
    unsigned* root2u= (unsigned*)alloc((size_t)N_NODES * C * 4);  // 7.2 MB (bf16x2)
    ushort*   h3u   = (ushort*)alloc((size_t)N_NODES * C * 2);    // 3.6 MB (fp8x2)
    ushort*   p18k0 = (ushort*)root1;                        // [N*C] bf16 (root1 dead by then)
    ushort*   p18k1 = (ushort*)root1 + (size_t)N_NODES * C;

    int nbH = (NBUCKETS * NBLK + 255) / 256;         // 391

    // ---- CSR build (zero global atomics; parallel bucket scan + fused weight prep) ----
    histA_kernel<<<NBLK, 256, 0, stream>>>(tgt, hist);
    scan1_kernel<<<nbH, 256, 0, stream>>>(hist, histx, bsum, NBUCKETS * NBLK);
    scan2p_prep_kernel<<<101, 512, 0, stream>>>(bsum, nbH,
                                                init_w1, root_w1, w1, init_w2, root_w2, w2,
                                                W1T, WmT, W2T, W3T);
    scan3_kernel<<<nbH, 256, 0, stream>>>(histx, bsum, NBUCKETS * NBLK, -1);
    scatterC_kernel<<<NBLK, 256, 0, stream>>>(src, tgt, histx, tmp);
    bucketD2_kernel<<<NBUCKETS, 256, 0, stream>>>(tmp, histx, rp, dinv, ssrc);

    int g1blocks = (N_NODES + 31) / 32;         // 3125 (dense1 32-node tiles)
    int gblocks  = (N_NODES + 63) / 64;         // 1563
    int pgrid    = (N_NODES + 3) / 4;           // 25000 (wave per node)

    // ---- layer 1 ----
    dense1_mfma<<<g1blocks, 256, 0, stream>>>(x, W1T, dinv, g1, root1);
    prop64_kernel<0><<<pgrid, 256, 0, stream>>>(g1, root1, b1, dinv, rp, ssrc, hk0, hk1, nullptr);
    dense_mid_mfma<<<gblocks, 256, 0, stream>>>(hk0, hk1, WmT, dinv, g2);
    prop64_kernel<1><<<pgrid, 256, 0, stream>>>(g2, root1, b1, dinv, rp, ssrc, nullptr, nullptr, yb);

    // ---- layer 2 ----
    dense_y2_mfma<<<gblocks, 256, 0, stream>>>(yb, W2T, dinv, h2u, root2u);
    prop18_kernel<0><<<pgrid, 256, 0, stream>>>(h2u, root2u, b2, dinv, rp, ssrc, p18k0, p18k1, nullptr);
    dense_last_mfma<<<gblocks, 256, 0, stream>>>(p18k0, p18k1, W3T, dinv, h3u);
    prop18_kernel<1><<<pgrid, 256, 0, stream>>>(h3u, root2u, b2, dinv, rp, ssrc, nullptr, nullptr, out);
}

// Round 18
// 311.718 us; speedup vs baseline: 1.0185x; 1.0185x over previous
//
#include <hip/hip_runtime.h>
#include <hip/hip_bf16.h>
#include <math.h>

#define N_NODES 100000
#define N_EDGES 1600000
#define F_IN 100
#define H 64
#define C 18
#define BSHIFT 8
#define BSIZE 256
#define NBUCKETS ((N_NODES + BSIZE - 1) >> BSHIFT)   // 391
#define NBLK 256
#define CHUNK (N_EDGES / NBLK)                       // 6250

typedef __attribute__((ext_vector_type(8))) short v8s;   // 8 bf16 (4 VGPRs)
typedef __attribute__((ext_vector_type(4))) float v4f;   // 4 f32 acc
typedef __attribute__((ext_vector_type(2))) float v2f;

// ----------------- bf16x2 / fp8x2 pack/unpack -----------------

__device__ __forceinline__ unsigned bf16_rne(float f) {
    unsigned u = __float_as_uint(f);
    return (u + 0x7FFFu + ((u >> 16) & 1u)) >> 16;
}
__device__ __forceinline__ unsigned pack_bf2(float a, float b) {
    return bf16_rne(a) | (bf16_rne(b) << 16);
}
__device__ __forceinline__ float2 unpack_bf2(unsigned u) {
    return make_float2(__uint_as_float(u << 16), __uint_as_float(u & 0xFFFF0000u));
}
// OCP e4m3 pair in a ushort: byte0 = a (stack0), byte1 = b (stack1). HW converts.
__device__ __forceinline__ ushort pack_fp8x2(float a, float b) {
    int r = __builtin_amdgcn_cvt_pk_fp8_f32(a, b, 0, false);
    return (ushort)(r & 0xFFFF);
}
__device__ __forceinline__ float2 unpack_fp8x2(ushort u) {
    v2f r = __builtin_amdgcn_cvt_pk_f32_fp8((int)u, false);
    return make_float2(r[0], r[1]);
}

// ----------------- scan helpers (for histx only) -----------------

__global__ void scan1_kernel(const int* __restrict__ cnt, int* __restrict__ excl,
                             int* __restrict__ bsum, int n) {
    __shared__ int tmp[256];
    int t = threadIdx.x;
    int i = blockIdx.x * 256 + t;
    int v = (i < n) ? cnt[i] : 0;
    tmp[t] = v;
    __syncthreads();
    for (int off = 1; off < 256; off <<= 1) {
        int xv = (t >= off) ? tmp[t - off] : 0;
        __syncthreads();
        tmp[t] += xv;
        __syncthreads();
    }
    if (i < n) excl[i] = tmp[t] - v;
    if (t == 255) bsum[blockIdx.x] = tmp[255];
}

// block 0: parallel exclusive scan of bsum[0..nb). blocks 1..: weight prep.
__global__ void __launch_bounds__(512) scan2p_prep_kernel(
        int* __restrict__ bsum, int nb,
        const float* __restrict__ iw1, const float* __restrict__ rw1,
        const float* __restrict__ w1,  const float* __restrict__ iw2,
        const float* __restrict__ rw2, const float* __restrict__ w2,
        ushort* __restrict__ W1T, ushort* __restrict__ WmT,
        ushort* __restrict__ W2T, ushort* __restrict__ W3T) {
    int t = threadIdx.x;
    if (blockIdx.x == 0) {
        __shared__ int s[512];
        int v = (t < nb) ? bsum[t] : 0;
        s[t] = v;
        __syncthreads();
        for (int off = 1; off < 512; off <<= 1) {
            int xv = (t >= off) ? s[t - off] : 0;
            __syncthreads();
            s[t] += xv;
            __syncthreads();
        }
        if (t < nb) bsum[t] = s[t] - v;   // exclusive
        return;
    }
    int gid = (blockIdx.x - 1) * 512 + t;
    if (gid < 32768) {                         // W1T: 4*64*128
        int idx = gid;
        int m = idx >> 13, nn = (idx >> 7) & 63, kk = idx & 127;
        int stk = m & 1, isWr = m >> 1;
        float v = 0.f;
        if (kk < F_IN) v = (isWr ? rw1 : iw1)[((size_t)stk * F_IN + kk) * 64 + nn];
        W1T[idx] = (ushort)bf16_rne(v);
    } else if (gid < 32768 + 8192) {           // WmT: 2*64*64
        int idx = gid - 32768;
        int stk = idx >> 12, g = (idx >> 6) & 63, f = idx & 63;
        WmT[idx] = (ushort)bf16_rne(w1[((size_t)stk * 64 + f) * 64 + g]);
    } else if (gid < 32768 + 8192 + 8192) {    // W2T: 4*32*64
        int idx = gid - 32768 - 8192;
        int m = idx >> 11, col = (idx >> 6) & 31, k = idx & 63;
        int stk = m & 1, isWr = m >> 1;
        float v = 0.f;
        if (col < C) v = (isWr ? rw2 : iw2)[((size_t)stk * H + k) * C + col];
        W2T[idx] = (ushort)bf16_rne(v);
    } else if (gid < 32768 + 8192 + 8192 + 2048) {  // W3T: 2*32*32
        int idx = gid - 32768 - 8192 - 8192;
        int stk = idx >> 10, col = (idx >> 5) & 31, k = idx & 31;
        float v = 0.f;
        if (col < C && k < C) v = w2[((size_t)stk * C + k) * C + col];
        W3T[idx] = (ushort)bf16_rne(v);
    }
}

__global__ void scan3_kernel(int* __restrict__ arr, const int* __restrict__ bsum,
                             int n, int sent) {
    int i = blockIdx.x * 256 + threadIdx.x;
    if (i < n) arr[i] += bsum[i >> 8];
    if (i == n && sent >= 0) arr[n] = sent;
}

// ----------------- bucket sort (no global atomics anywhere) -----------------

__global__ void __launch_bounds__(256) histA_kernel(const int* __restrict__ tgt,
                                                    int* __restrict__ hist) {
    __shared__ int h[NBUCKETS];
    int blk = blockIdx.x, t = threadIdx.x;
    for (int i = t; i < NBUCKETS; i += 256) h[i] = 0;
    __syncthreads();
    int e0 = blk * CHUNK, e1 = e0 + CHUNK;
    for (int e = e0 + t; e < e1; e += 256) atomicAdd(&h[tgt[e] >> BSHIFT], 1);
    __syncthreads();
    for (int i = t; i < NBUCKETS; i += 256) hist[i * NBLK + blk] = h[i];
}

// packed word = src | (t_local << 17)   (src < 2^17, t_local < 256)
__global__ void __launch_bounds__(256) scatterC_kernel(
        const int* __restrict__ src, const int* __restrict__ tgt,
        const int* __restrict__ histx, unsigned* __restrict__ tmp) {
    __shared__ int cur[NBUCKETS];
    int blk = blockIdx.x, t = threadIdx.x;
    for (int i = t; i < NBUCKETS; i += 256) cur[i] = histx[i * NBLK + blk];
    __syncthreads();
    int e0 = blk * CHUNK, e1 = e0 + CHUNK;
    for (int e = e0 + t; e < e1; e += 256) {
        int s = src[e], tg = tgt[e];
        int b = tg >> BSHIFT;
        int pos = atomicAdd(&cur[b], 1);
        tmp[pos] = (unsigned)s | ((unsigned)(tg & (BSIZE - 1)) << 17);
    }
}

// one block per bucket: LDS hist of t_local -> degree; LDS scan -> rp; node-sorted ssrc.
__global__ void __launch_bounds__(256) bucketD2_kernel(
        const unsigned* __restrict__ tmp, const int* __restrict__ histx,
        int* __restrict__ rp, float* __restrict__ dinv, int* __restrict__ ssrc) {
    __shared__ int cnt_l[BSIZE];
    __shared__ int scan_l[BSIZE];
    int b = blockIdx.x;
    int t = threadIdx.x;
    int e_lo = histx[(size_t)b * NBLK];
    int e_hi = (b + 1 < NBUCKETS) ? histx[(size_t)(b + 1) * NBLK] : N_EDGES;
    int n_lo = b << BSHIFT;
    int n_hi = min(n_lo + BSIZE, N_NODES);
    int nn = n_hi - n_lo;
    cnt_l[t] = 0;
    __syncthreads();
    for (int e = e_lo + t; e < e_hi; e += 256)
        atomicAdd(&cnt_l[(int)(tmp[e] >> 17)], 1);
    __syncthreads();
    int v = cnt_l[t];
    scan_l[t] = v;
    __syncthreads();
    for (int off = 1; off < 256; off <<= 1) {
        int xv = (t >= off) ? scan_l[t - off] : 0;
        __syncthreads();
        scan_l[t] += xv;
        __syncthreads();
    }
    int my_start = e_lo + scan_l[t] - v;
    if (t < nn) {
        rp[n_lo + t] = my_start;
        dinv[n_lo + t] = (v > 0) ? rsqrtf((float)v) : 0.f;
    }
    if (b == NBUCKETS - 1 && t == 0) rp[N_NODES] = N_EDGES;
    __syncthreads();
    cnt_l[t] = my_start;
    __syncthreads();
    for (int e = e_lo + t; e < e_hi; e += 256) {
        unsigned p = tmp[e];
        int s = (int)(p & 0x1FFFFu);
        int tl = (int)(p >> 17);
        int pos = atomicAdd(&cnt_l[tl], 1);
        ssrc[pos] = s;
    }
}

// ----------------- MFMA fragment conventions -----------------
// A-frag (16x16x32): lane(q=lane>>4, cl=lane&15) holds A[row=cl][k=q*8+j].
// B-frag: lane holds B[k=q*8+j][col=cl] -> weights stored [col][k], 16B/lane.
// C/D: col=lane&15, row=q*4+reg (m89-verified).
// LDS A-tiles: granule(16B) index XOR'd with row bits to kill bank conflicts.

// dense1: 32-node tiles (grid 3125), float4 x loads, bf16-convert in staging.
// g AND root outputs: fp8x2 (stack0,stack1) per (node,col) -- 12.8 MB each.
__global__ void __launch_bounds__(256) dense1_mfma(
        const float* __restrict__ x, const ushort* __restrict__ W1T,
        const float* __restrict__ dinv,
        ushort* __restrict__ g, ushort* __restrict__ root) {
    __shared__ char xs[32 * 256];   // 8KB: 32 rows x 128 bf16 (K pad), swizzled
    int tid = threadIdx.x;
    int b0 = blockIdx.x * 32;
    // stage: 32 rows x 25 float4 (row bases 16B-aligned: 400 = 25*16)
    for (int i = tid; i < 32 * 25; i += 256) {
        int row = i / 25, f4 = i - row * 25;
        int grow = b0 + row;
        float4 v = make_float4(0.f, 0.f, 0.f, 0.f);
        if (grow < N_NODES) v = *(const float4*)(x + (size_t)grow * F_IN + f4 * 4);
        unsigned p0 = pack_bf2(v.x, v.y);
        unsigned p1 = pack_bf2(v.z, v.w);
        int pr = f4 * 2;                       // u32-pair index; pr and pr+1 share a granule
        int gr = (pr >> 2) ^ (row & 7);
        char* base = xs + row * 256 + (gr << 4) + (pr & 3) * 4;
        *(unsigned*)base = p0;
        *(unsigned*)(base + 4) = p1;
    }
    // zero-pad K cols 100..127 (u32 pairs 50..63)
    for (int i = tid; i < 32 * 14; i += 256) {
        int row = i / 14, pr = 50 + (i - row * 14);
        int gr = (pr >> 2) ^ (row & 7);
        *(unsigned*)(xs + row * 256 + (gr << 4) + (pr & 3) * 4) = 0;
    }
    __syncthreads();
    int lane = tid & 63;
    int w = __builtin_amdgcn_readfirstlane(tid >> 6);
    int q = lane >> 4, cl = lane & 15;
    int isWr = w >> 1;
    int colbase = (w & 1) * 32;
    v8s bfr[2][2][4];   // [stk][ntile][kstep]
    #pragma unroll
    for (int stk = 0; stk < 2; ++stk)
        #pragma unroll
        for (int nt = 0; nt < 2; ++nt)
            #pragma unroll
            for (int ks = 0; ks < 4; ++ks) {
                const ushort* p = W1T + ((size_t)(isWr * 2 + stk) * 64 + colbase + nt * 16 + cl) * 128
                                  + ks * 32 + q * 8;
                bfr[stk][nt][ks] = *(const v8s*)p;
            }
    #pragma unroll
    for (int mt = 0; mt < 2; ++mt) {
        v8s afr[4];
        #pragma unroll
        for (int ks = 0; ks < 4; ++ks) {
            int row = mt * 16 + cl;
            int gr = (ks * 4 + q) ^ (row & 7);
            afr[ks] = *(const v8s*)(xs + row * 256 + (gr << 4));
        }
        v4f acc[2][2];
        #pragma unroll
        for (int stk = 0; stk < 2; ++stk)
            #pragma unroll
            for (int nt = 0; nt < 2; ++nt) {
                v4f a = {0.f, 0.f, 0.f, 0.f};
                #pragma unroll
                for (int ks = 0; ks < 4; ++ks)
                    a = __builtin_amdgcn_mfma_f32_16x16x32_bf16(afr[ks], bfr[stk][nt][ks], a, 0, 0, 0);
                acc[stk][nt] = a;
            }
        #pragma unroll
        for (int nt = 0; nt < 2; ++nt)
            #pragma unroll
            for (int reg = 0; reg < 4; ++reg) {
                int node = b0 + mt * 16 + q * 4 + reg;
                if (node < N_NODES) {
                    int col = colbase + nt * 16 + cl;
                    if (isWr == 0) {
                        float dv = dinv[node];
                        g[(size_t)node * 64 + col] = pack_fp8x2(dv * acc[0][nt][reg], dv * acc[1][nt][reg]);
                    } else {
                        root[(size_t)node * 64 + col] = pack_fp8x2(acc[0][nt][reg], acc[1][nt][reg]);
                    }
                }
            }
    }
}

// dense_mid: hk0/hk1 planar bf16 -> fp8x2 g2 (x dinv). block = 64 nodes.
__global__ void __launch_bounds__(256) dense_mid_mfma(
        const ushort* __restrict__ hk0, const ushort* __restrict__ hk1,
        const ushort* __restrict__ WmT, const float* __restrict__ dinv,
        ushort* __restrict__ g2) {
    __shared__ char hs[2 * 64 * 128];   // 16KB: [stk][row][64 bf16], swizzled
    int tid = threadIdx.x;
    int b0 = blockIdx.x * 64;
    for (int i = tid; i < 1024; i += 256) {          // 2 tiles * 64 rows * 8 granules
        int stk = i >> 9, rem = i & 511, row = rem >> 3, gr = rem & 7;
        int grow = b0 + row;
        uint4 v = make_uint4(0, 0, 0, 0);
        const ushort* srcp = stk ? hk1 : hk0;
        if (grow < N_NODES) v = *(const uint4*)(srcp + (size_t)grow * 64 + gr * 8);
        *(uint4*)(hs + stk * 8192 + row * 128 + ((gr ^ (row & 7)) << 4)) = v;
    }
    __syncthreads();
    int lane = tid & 63;
    int w = __builtin_amdgcn_readfirstlane(tid >> 6);
    int q = lane >> 4, cl = lane & 15;
    v8s bfr[2][2];   // [stk][kstep]
    #pragma unroll
    for (int stk = 0; stk < 2; ++stk)
        #pragma unroll
        for (int ks = 0; ks < 2; ++ks)
            bfr[stk][ks] = *(const v8s*)(WmT + ((size_t)stk * 64 + w * 16 + cl) * 64 + ks * 32 + q * 8);
    #pragma unroll
    for (int mt = 0; mt < 4; ++mt) {
        v4f acc[2];
        #pragma unroll
        for (int stk = 0; stk < 2; ++stk) {
            v4f a = {0.f, 0.f, 0.f, 0.f};
            #pragma unroll
            for (int ks = 0; ks < 2; ++ks) {
                int row = mt * 16 + cl;
                int gr = (ks * 4 + q) ^ (row & 7);
                v8s af = *(const v8s*)(hs + stk * 8192 + row * 128 + (gr << 4));
                a = __builtin_amdgcn_mfma_f32_16x16x32_bf16(af, bfr[stk][ks], a, 0, 0, 0);
            }
            acc[stk] = a;
        }
        #pragma unroll
        for (int reg = 0; reg < 4; ++reg) {
            int node = b0 + mt * 16 + q * 4 + reg;
            if (node < N_NODES) {
                float dv = dinv[node];
                g2[(size_t)node * 64 + w * 16 + cl] = pack_fp8x2(dv * acc[0][reg], dv * acc[1][reg]);
            }
        }
    }
}

// dense_y2: yb planar bf16 -> h2 fp8x2 (x dinv) / root2 bf16x2. block = 64 nodes.
__global__ void __launch_bounds__(256) dense_y2_mfma(
        const ushort* __restrict__ yb, const ushort* __restrict__ W2T,
        const float* __restrict__ dinv,
        ushort* __restrict__ h2, unsigned* __restrict__ root2) {
    __shared__ char ys[64 * 128];   // 8KB: 64 rows x 64 bf16, swizzled
    int tid = threadIdx.x;
    int b0 = blockIdx.x * 64;
    for (int i = tid; i < 512; i += 256) {           // 64 rows * 8 granules
        int row = i >> 3, gr = i & 7;
        int grow = b0 + row;
        uint4 v = make_uint4(0, 0, 0, 0);
        if (grow < N_NODES) v = *(const uint4*)(yb + (size_t)grow * 64 + gr * 8);
        *(uint4*)(ys + row * 128 + ((gr ^ (row & 7)) << 4)) = v;
    }
    __syncthreads();
    int lane = tid & 63;
    int w = __builtin_amdgcn_readfirstlane(tid >> 6);
    int q = lane >> 4, cl = lane & 15;
    int isWr = w >> 1;
    int mbase = (w & 1) * 2;
    v8s bfr[2][2][2];   // [stk][ntile][kstep]
    #pragma unroll
    for (int stk = 0; stk < 2; ++stk)
        #pragma unroll
        for (int nt = 0; nt < 2; ++nt)
            #pragma unroll
            for (int ks = 0; ks < 2; ++ks)
                bfr[stk][nt][ks] = *(const v8s*)(W2T + ((size_t)(isWr * 2 + stk) * 32 + nt * 16 + cl) * 64
                                                 + ks * 32 + q * 8);
    #pragma unroll
    for (int mi = 0; mi < 2; ++mi) {
        int mt = mbase + mi;
        v8s afr[2];
        #pragma unroll
        for (int ks = 0; ks < 2; ++ks) {
            int row = mt * 16 + cl;
            int gr = (ks * 4 + q) ^ (row & 7);
            afr[ks] = *(const v8s*)(ys + row * 128 + (gr << 4));
        }
        v4f acc[2][2];
        #pragma unroll
        for (int stk = 0; stk < 2; ++stk)
            #pragma unroll
            for (int nt = 0; nt < 2; ++nt) {
                v4f a = {0.f, 0.f, 0.f, 0.f};
                #pragma unroll
                for (int ks = 0; ks < 2; ++ks)
                    a = __builtin_amdgcn_mfma_f32_16x16x32_bf16(afr[ks], bfr[stk][nt][ks], a, 0, 0, 0);
                acc[stk][nt] = a;
            }
        #pragma unroll
        for (int nt = 0; nt < 2; ++nt)
            #pragma unroll
            for (int reg = 0; reg < 4; ++reg) {
                int node = b0 + mt * 16 + q * 4 + reg;
                int col = nt * 16 + cl;
                if (node < N_NODES && col < C) {
                    if (isWr == 0) {
                        float dv = dinv[node];
                        h2[(size_t)node * C + col] = pack_fp8x2(dv * acc[0][nt][reg], dv * acc[1][nt][reg]);
                    } else {
                        root2[(size_t)node * C + col] = pack_bf2(acc[0][nt][reg], acc[1][nt][reg]);
                    }
                }
            }
    }
}

// dense_last: p18k0/p18k1 planar bf16 -> h3 fp8x2 (x dinv). block = 64 nodes.
__global__ void __launch_bounds__(256) dense_last_mfma(
        const ushort* __restrict__ ok0, const ushort* __restrict__ ok1,
        const ushort* __restrict__ W3T, const float* __restrict__ dinv,
        ushort* __restrict__ h3) {
    __shared__ char hs[2 * 64 * 64];   // 8KB: [stk][row][32 bf16], swizzle gr^(row&3)
    int tid = threadIdx.x;
    int b0 = blockIdx.x * 64;
    for (int i = tid; i < 2048; i += 256) ((unsigned*)hs)[i] = 0;
    __syncthreads();
    for (int i = tid; i < 4096; i += 256) {          // 2 stk * 64 rows * 32 cols
        int stk = i >> 11, row = (i >> 5) & 63, col = i & 31;
        int node = b0 + row;
        if (col < C && node < N_NODES) {
            ushort v = (stk ? ok1 : ok0)[(size_t)node * C + col];
            int gr = (col >> 3) ^ (row & 3);
            *(ushort*)(hs + stk * 4096 + row * 64 + (gr << 4) + (col & 7) * 2) = v;
        }
    }
    __syncthreads();
    int lane = tid & 63;
    int w = __builtin_amdgcn_readfirstlane(tid >> 6);
    int q = lane >> 4, cl = lane & 15;
    v8s bfr[2][2];   // [stk][ntile]
    #pragma unroll
    for (int stk = 0; stk < 2; ++stk)
        #pragma unroll
        for (int nt = 0; nt < 2; ++nt)
            bfr[stk][nt] = *(const v8s*)(W3T + ((size_t)stk * 32 + nt * 16 + cl) * 32 + q * 8);
    int row = w * 16 + cl;
    int gr = q ^ (row & 3);
    v8s af0 = *(const v8s*)(hs + row * 64 + (gr << 4));
    v8s af1 = *(const v8s*)(hs + 4096 + row * 64 + (gr << 4));
    v4f acc[2][2];
    #pragma unroll
    for (int nt = 0; nt < 2; ++nt) {
        acc[0][nt] = __builtin_amdgcn_mfma_f32_16x16x32_bf16(af0, bfr[0][nt], (v4f){0.f,0.f,0.f,0.f}, 0, 0, 0);
        acc[1][nt] = __builtin_amdgcn_mfma_f32_16x16x32_bf16(af1, bfr[1][nt], (v4f){0.f,0.f,0.f,0.f}, 0, 0, 0);
    }
    #pragma unroll
    for (int nt = 0; nt < 2; ++nt)
        #pragma unroll
        for (int reg = 0; reg < 4; ++reg) {
            int node = b0 + w * 16 + q * 4 + reg;
            int col = nt * 16 + cl;
            if (node < N_NODES && col < C) {
                float dv = dinv[node];
                h3[(size_t)node * C + col] = pack_fp8x2(dv * acc[0][nt][reg], dv * acc[1][nt][reg]);
            }
        }
}

// ----------------- propagation -----------------

// prop64: wave per node, 64 lanes = 64 cols, fp8x2 table + fp8x2 root, unroll-8.
// root/dinv loads hoisted BEFORE the gather loop (latency overlap).
template <int FINAL>
__global__ void __launch_bounds__(256) prop64_kernel(
        const ushort* __restrict__ g, const ushort* __restrict__ root,
        const float* __restrict__ b, const float* __restrict__ dinv,
        const int* __restrict__ rp, const int* __restrict__ ssrc,
        ushort* __restrict__ ok0, ushort* __restrict__ ok1, ushort* __restrict__ yb) {
    int lane = threadIdx.x & 63;
    int wid = __builtin_amdgcn_readfirstlane((int)((blockIdx.x * 256 + threadIdx.x) >> 6));
    if (wid >= N_NODES) return;
    int e0 = rp[wid], e1 = rp[wid + 1];
    ushort rtu = root[(size_t)wid * H + lane];   // hoisted: hides under gather loop
    float dv = dinv[wid];
    float bl0 = b[lane], bl1 = b[H + lane];
    float a0 = 0.f, a1 = 0.f;
    int e = e0;
    for (; e + 8 <= e1; e += 8) {
        ushort u[8];
        #pragma unroll
        for (int j = 0; j < 8; ++j) u[j] = g[(size_t)ssrc[e + j] * H + lane];
        #pragma unroll
        for (int j = 0; j < 8; ++j) { float2 v = unpack_fp8x2(u[j]); a0 += v.x; a1 += v.y; }
    }
    for (; e < e1; ++e) {
        float2 v = unpack_fp8x2(g[(size_t)ssrc[e] * H + lane]);
        a0 += v.x; a1 += v.y;
    }
    float2 rt = unpack_fp8x2(rtu);
    float o0 = fmaxf(fmaf(dv, a0, rt.x + bl0), 0.f);
    float o1 = fmaxf(fmaf(dv, a1, rt.y + bl1), 0.f);
    if (FINAL) {
        yb[(size_t)wid * H + lane] = (ushort)bf16_rne(0.5f * (o0 + o1));
    } else {
        ok0[(size_t)wid * H + lane] = (ushort)bf16_rne(o0);
        ok1[(size_t)wid * H + lane] = (ushort)bf16_rne(o1);
    }
}

// prop18: wave per node; each gather instruction loads TWO edges' rows
// (lane half selects between two SCALAR src indices -> e stays wave-uniform,
// ssrc stays on the s_load path). Combine halves via shfl_xor(32).
template <int FINAL>
__global__ void __launch_bounds__(256) prop18_kernel(
        const ushort* __restrict__ g, const unsigned* __restrict__ root,
        const float* __restrict__ b, const float* __restrict__ dinv,
        const int* __restrict__ rp, const int* __restrict__ ssrc,
        ushort* __restrict__ ok0, ushort* __restrict__ ok1, float* __restrict__ outp) {
    int lane = threadIdx.x & 63;
    int wid = __builtin_amdgcn_readfirstlane((int)((blockIdx.x * 256 + threadIdx.x) >> 6));
    if (wid >= N_NODES) return;
    int e0 = rp[wid], e1 = rp[wid + 1];
    bool hi = lane >= 32;
    int c32 = lane & 31;
    bool actG = c32 < C;
    int c = actG ? c32 : 0;
    unsigned rtu = root[(size_t)wid * C + c];    // hoisted
    float dv = dinv[wid];
    float bl0 = b[c], bl1 = b[C + c];
    float a0 = 0.f, a1 = 0.f;
    int e = e0;
    for (; e + 16 <= e1; e += 16) {   // 8 instructions x 2 edges each
        ushort u[8];
        #pragma unroll
        for (int j = 0; j < 8; ++j) {
            int s0 = ssrc[e + 2 * j];        // scalar (e uniform)
            int s1 = ssrc[e + 2 * j + 1];    // scalar
            int srow = hi ? s1 : s0;
            u[j] = g[(size_t)srow * C + c];
        }
        if (actG) {
            #pragma unroll
            for (int j = 0; j < 8; ++j) { float2 v = unpack_fp8x2(u[j]); a0 += v.x; a1 += v.y; }
        }
    }
    for (; e + 2 <= e1; e += 2) {
        int s0 = ssrc[e];
        int s1 = ssrc[e + 1];
        int srow = hi ? s1 : s0;
        float2 v = unpack_fp8x2(g[(size_t)srow * C + c]);
        if (actG) { a0 += v.x; a1 += v.y; }
    }
    if (e < e1) {   // odd last edge: half 0 only
        int s0 = ssrc[e];
        float2 v = unpack_fp8x2(g[(size_t)s0 * C + c]);
        if (actG && !hi) { a0 += v.x; a1 += v.y; }
    }
    a0 += __shfl_xor(a0, 32, 64);
    a1 += __shfl_xor(a1, 32, 64);
    bool actO = lane < C;
    if (!FINAL) {
        if (actO) {
            float2 rt = unpack_bf2(rtu);
            float o0 = fmaxf(fmaf(dv, a0, rt.x + bl0), 0.f);
            float o1 = fmaxf(fmaf(dv, a1, rt.y + bl1), 0.f);
            ok0[(size_t)wid * C + c] = (ushort)bf16_rne(o0);
            ok1[(size_t)wid * C + c] = (ushort)bf16_rne(o1);
        }
    } else {
        float m = -INFINITY;
        if (actO) {
            float2 rt = unpack_bf2(rtu);
            float o0 = fmaxf(fmaf(dv, a0, rt.x + bl0), 0.f);
            float o1 = fmaxf(fmaf(dv, a1, rt.y + bl1), 0.f);
            m = 0.5f * (o0 + o1);
        }
        float mx = m;
        #pragma unroll
        for (int off = 16; off >= 1; off >>= 1) mx = fmaxf(mx, __shfl_xor(mx, off, 64));
        float ex = actO ? __expf(m - mx) : 0.f;
        float sum = ex;
        #pragma unroll
        for (int off = 16; off >= 1; off >>= 1) sum += __shfl_xor(sum, off, 64);
        if (actO) outp[(size_t)wid * C + c] = m - mx - logf(sum);
    }
}

// ----------------- launch -----------------

extern "C" void kernel_launch(void* const* d_in, const int* in_sizes, int n_in,
                              void* d_out, int out_size, void* d_ws, size_t ws_size,
                              hipStream_t stream) {
    const float* x        = (const float*)d_in[0];
    const int*   ei       = (const int*)d_in[1];
    const float* init_w1  = (const float*)d_in[2];
    const float* w1       = (const float*)d_in[3];
    const float* root_w1  = (const float*)d_in[4];
    const float* b1       = (const float*)d_in[5];
    const float* init_w2  = (const float*)d_in[6];
    const float* w2       = (const float*)d_in[7];
    const float* root_w2  = (const float*)d_in[8];
    const float* b2       = (const float*)d_in[9];
    const int* src = ei;
    const int* tgt = ei + N_EDGES;
    float* out = (float*)d_out;

    char* w = (char*)d_ws;
    size_t off = 0;
    auto alloc = [&](size_t bytes) -> char* {
        char* p = w + off;
        off += (bytes + 255) & ~(size_t)255;
        return p;
    };
    int*      rp    = (int*)alloc((size_t)(N_NODES + 1) * 4);
    float*    dinv  = (float*)alloc((size_t)N_NODES * 4);
    int*      bsum  = (int*)alloc(512 * 4);
    int*      hist  = (int*)alloc((size_t)NBUCKETS * NBLK * 4);
    int*      histx = (int*)alloc((size_t)NBUCKETS * NBLK * 4);
    unsigned* tmp   = (unsigned*)alloc((size_t)N_EDGES * 4);
    int*      ssrc  = (int*)alloc((size_t)N_EDGES * 4);
    ushort*   W1T   = (ushort*)alloc((size_t)4 * 64 * 128 * 2);
    ushort*   WmT   = (ushort*)alloc((size_t)2 * 64 * 64 * 2);
    ushort*   W2T   = (ushort*)alloc((size_t)4 * 32 * 64 * 2);
    ushort*   W3T   = (ushort*)alloc((size_t)2 * 32 * 32 * 2);
    ushort*   g1    = (ushort*)alloc((size_t)N_NODES * H * 2);    // 12.8 MB (fp8x2)
    ushort*   root1 = (ushort*)alloc((size_t)N_NODES * H * 2);    // 12.8 MB (fp8x2)
    ushort*   hk0   = (ushort*)alloc((size_t)N_NODES * H * 2);    // 12.8 MB
    ushort*   hk1   = (ushort*)alloc((size_t)N_NODES * H * 2);    // 12.8 MB
    ushort*   g2    = (ushort*)alloc((size_t)N_NODES * H * 2);    // 12.8 MB (fp8x2)
    ushort*   yb    = (ushort*)alloc((size_t)N_NODES * H * 2);    // 12.8 MB
    ushort*   h2u   = (ushort*)alloc((size_t)N_NODES * C * 2);    // 3.6 MB (fp8x2)
    unsigned* root2u= (unsigned*)alloc((size_t)N_NODES * C * 4);  // 7.2 MB (bf16x2)
    ushort*   h3u   = (ushort*)alloc((size_t)N_NODES * C * 2);    // 3.6 MB (fp8x2)
    ushort*   p18k0 = (ushort*)g1;                           // [N*C] bf16 (g1 dead by then)
    ushort*   p18k1 = (ushort*)g1 + (size_t)N_NODES * C;

    int nbH = (NBUCKETS * NBLK + 255) / 256;         // 391

    // ---- CSR build (zero global atomics; parallel bucket scan + fused weight prep) ----
    histA_kernel<<<NBLK, 256, 0, stream>>>(tgt, hist);
    scan1_kernel<<<nbH, 256, 0, stream>>>(hist, histx, bsum, NBUCKETS * NBLK);
    scan2p_prep_kernel<<<101, 512, 0, stream>>>(bsum, nbH,
                                                init_w1, root_w1, w1, init_w2, root_w2, w2,
                                                W1T, WmT, W2T, W3T);
    scan3_kernel<<<nbH, 256, 0, stream>>>(histx, bsum, NBUCKETS * NBLK, -1);
    scatterC_kernel<<<NBLK, 256, 0, stream>>>(src, tgt, histx, tmp);
    bucketD2_kernel<<<NBUCKETS, 256, 0, stream>>>(tmp, histx, rp, dinv, ssrc);

    int g1blocks = (N_NODES + 31) / 32;         // 3125 (dense1 32-node tiles)
    int gblocks  = (N_NODES + 63) / 64;         // 1563
    int pgrid    = (N_NODES + 3) / 4;           // 25000 (wave per node)

    // ---- layer 1 ----
    dense1_mfma<<<g1blocks, 256, 0, stream>>>(x, W1T, dinv, g1, root1);
    prop64_kernel<0><<<pgrid, 256, 0, stream>>>(g1, root1, b1, dinv, rp, ssrc, hk0, hk1, nullptr);
    dense_mid_mfma<<<gblocks, 256, 0, stream>>>(hk0, hk1, WmT, dinv, g2);
    prop64_kernel<1><<<pgrid, 256, 0, stream>>>(g2, root1, b1, dinv, rp, ssrc, nullptr, nullptr, yb);

    // ---- layer 2 ----
    dense_y2_mfma<<<gblocks, 256, 0, stream>>>(yb, W2T, dinv, h2u, root2u);
    prop18_kernel<0><<<pgrid, 256, 0, stream>>>(h2u, root2u, b2, dinv, rp, ssrc, p18k0, p18k1, nullptr);
    dense_last_mfma<<<gblocks, 256, 0, stream>>>(p18k0, p18k1, W3T, dinv, h3u);
    prop18_kernel<1><<<pgrid, 256, 0, stream>>>(h3u, root2u, b2, dinv, rp, ssrc, nullptr, nullptr, out);
}

// Round 19
// 309.492 us; speedup vs baseline: 1.0258x; 1.0072x over previous
//
#include <hip/hip_runtime.h>
#include <hip/hip_bf16.h>
#include <math.h>

#define N_NODES 100000
#define N_EDGES 1600000
#define F_IN 100
#define H 64
#define C 18
#define BSHIFT 8
#define BSIZE 256
#define NBUCKETS ((N_NODES + BSIZE - 1) >> BSHIFT)   // 391
#define NBLK 256
#define CHUNK (N_EDGES / NBLK)                       // 6250

typedef __attribute__((ext_vector_type(8))) short v8s;   // 8 bf16 (4 VGPRs)
typedef __attribute__((ext_vector_type(4))) float v4f;   // 4 f32 acc
typedef __attribute__((ext_vector_type(2))) float v2f;

// ----------------- bf16x2 / fp8x2 pack/unpack -----------------

__device__ __forceinline__ unsigned bf16_rne(float f) {
    unsigned u = __float_as_uint(f);
    return (u + 0x7FFFu + ((u >> 16) & 1u)) >> 16;
}
__device__ __forceinline__ unsigned pack_bf2(float a, float b) {
    return bf16_rne(a) | (bf16_rne(b) << 16);
}
__device__ __forceinline__ float2 unpack_bf2(unsigned u) {
    return make_float2(__uint_as_float(u << 16), __uint_as_float(u & 0xFFFF0000u));
}
// OCP e4m3 pair in a ushort: byte0 = a (stack0), byte1 = b (stack1). HW converts.
__device__ __forceinline__ ushort pack_fp8x2(float a, float b) {
    int r = __builtin_amdgcn_cvt_pk_fp8_f32(a, b, 0, false);
    return (ushort)(r & 0xFFFF);
}
__device__ __forceinline__ float2 unpack_fp8x2(ushort u) {
    v2f r = __builtin_amdgcn_cvt_pk_f32_fp8((int)u, false);
    return make_float2(r[0], r[1]);
}

// ----------------- scan helpers (for histx only) -----------------

__global__ void scan1_kernel(const int* __restrict__ cnt, int* __restrict__ excl,
                             int* __restrict__ bsum, int n) {
    __shared__ int tmp[256];
    int t = threadIdx.x;
    int i = blockIdx.x * 256 + t;
    int v = (i < n) ? cnt[i] : 0;
    tmp[t] = v;
    __syncthreads();
    for (int off = 1; off < 256; off <<= 1) {
        int xv = (t >= off) ? tmp[t - off] : 0;
        __syncthreads();
        tmp[t] += xv;
        __syncthreads();
    }
    if (i < n) excl[i] = tmp[t] - v;
    if (t == 255) bsum[blockIdx.x] = tmp[255];
}

// block 0: parallel exclusive scan of bsum[0..nb). blocks 1..: weight prep.
__global__ void __launch_bounds__(512) scan2p_prep_kernel(
        int* __restrict__ bsum, int nb,
        const float* __restrict__ iw1, const float* __restrict__ rw1,
        const float* __restrict__ w1,  const float* __restrict__ iw2,
        const float* __restrict__ rw2, const float* __restrict__ w2,
        ushort* __restrict__ W1T, ushort* __restrict__ WmT,
        ushort* __restrict__ W2T, ushort* __restrict__ W3T) {
    int t = threadIdx.x;
    if (blockIdx.x == 0) {
        __shared__ int s[512];
        int v = (t < nb) ? bsum[t] : 0;
        s[t] = v;
        __syncthreads();
        for (int off = 1; off < 512; off <<= 1) {
            int xv = (t >= off) ? s[t - off] : 0;
            __syncthreads();
            s[t] += xv;
            __syncthreads();
        }
        if (t < nb) bsum[t] = s[t] - v;   // exclusive
        return;
    }
    int gid = (blockIdx.x - 1) * 512 + t;
    if (gid < 32768) {                         // W1T: 4*64*128
        int idx = gid;
        int m = idx >> 13, nn = (idx >> 7) & 63, kk = idx & 127;
        int stk = m & 1, isWr = m >> 1;
        float v = 0.f;
        if (kk < F_IN) v = (isWr ? rw1 : iw1)[((size_t)stk * F_IN + kk) * 64 + nn];
        W1T[idx] = (ushort)bf16_rne(v);
    } else if (gid < 32768 + 8192) {           // WmT: 2*64*64
        int idx = gid - 32768;
        int stk = idx >> 12, g = (idx >> 6) & 63, f = idx & 63;
        WmT[idx] = (ushort)bf16_rne(w1[((size_t)stk * 64 + f) * 64 + g]);
    } else if (gid < 32768 + 8192 + 8192) {    // W2T: 4*32*64
        int idx = gid - 32768 - 8192;
        int m = idx >> 11, col = (idx >> 6) & 31, k = idx & 63;
        int stk = m & 1, isWr = m >> 1;
        float v = 0.f;
        if (col < C) v = (isWr ? rw2 : iw2)[((size_t)stk * H + k) * C + col];
        W2T[idx] = (ushort)bf16_rne(v);
    } else if (gid < 32768 + 8192 + 8192 + 2048) {  // W3T: 2*32*32
        int idx = gid - 32768 - 8192 - 8192;
        int stk = idx >> 10, col = (idx >> 5) & 31, k = idx & 31;
        float v = 0.f;
        if (col < C && k < C) v = w2[((size_t)stk * C + k) * C + col];
        W3T[idx] = (ushort)bf16_rne(v);
    }
}

// ----------------- bucket sort (no global atomics; scan3 folded into consumers) ---

__global__ void __launch_bounds__(256) histA_kernel(const int* __restrict__ tgt,
                                                    int* __restrict__ hist) {
    __shared__ int h[NBUCKETS];
    int blk = blockIdx.x, t = threadIdx.x;
    for (int i = t; i < NBUCKETS; i += 256) h[i] = 0;
    __syncthreads();
    int e0 = blk * CHUNK, e1 = e0 + CHUNK;
    for (int e = e0 + t; e < e1; e += 256) atomicAdd(&h[tgt[e] >> BSHIFT], 1);
    __syncthreads();
    for (int i = t; i < NBUCKETS; i += 256) hist[i * NBLK + blk] = h[i];
}

// packed word = src | (t_local << 17)   (src < 2^17, t_local < 256)
// histx holds block-local exclusive scans; bsum adds the global block offset.
__global__ void __launch_bounds__(256) scatterC_kernel(
        const int* __restrict__ src, const int* __restrict__ tgt,
        const int* __restrict__ histx, const int* __restrict__ bsum,
        unsigned* __restrict__ tmp) {
    __shared__ int cur[NBUCKETS];
    int blk = blockIdx.x, t = threadIdx.x;
    for (int i = t; i < NBUCKETS; i += 256) {
        int gi = i * NBLK + blk;
        cur[i] = histx[gi] + bsum[gi >> 8];
    }
    __syncthreads();
    int e0 = blk * CHUNK, e1 = e0 + CHUNK;
    for (int e = e0 + t; e < e1; e += 256) {
        int s = src[e], tg = tgt[e];
        int b = tg >> BSHIFT;
        int pos = atomicAdd(&cur[b], 1);
        tmp[pos] = (unsigned)s | ((unsigned)(tg & (BSIZE - 1)) << 17);
    }
}

// one block per bucket: LDS hist of t_local -> degree; LDS scan -> rp; node-sorted ssrc.
__global__ void __launch_bounds__(256) bucketD2_kernel(
        const unsigned* __restrict__ tmp, const int* __restrict__ histx,
        const int* __restrict__ bsum,
        int* __restrict__ rp, float* __restrict__ dinv, int* __restrict__ ssrc) {
    __shared__ int cnt_l[BSIZE];
    __shared__ int scan_l[BSIZE];
    int b = blockIdx.x;
    int t = threadIdx.x;
    int gi_lo = b * NBLK;
    int e_lo = histx[gi_lo] + bsum[gi_lo >> 8];
    int e_hi = N_EDGES;
    if (b + 1 < NBUCKETS) {
        int gi_hi = (b + 1) * NBLK;
        e_hi = histx[gi_hi] + bsum[gi_hi >> 8];
    }
    int n_lo = b << BSHIFT;
    int n_hi = min(n_lo + BSIZE, N_NODES);
    int nn = n_hi - n_lo;
    cnt_l[t] = 0;
    __syncthreads();
    for (int e = e_lo + t; e < e_hi; e += 256)
        atomicAdd(&cnt_l[(int)(tmp[e] >> 17)], 1);
    __syncthreads();
    int v = cnt_l[t];
    scan_l[t] = v;
    __syncthreads();
    for (int off = 1; off < 256; off <<= 1) {
        int xv = (t >= off) ? scan_l[t - off] : 0;
        __syncthreads();
        scan_l[t] += xv;
        __syncthreads();
    }
    int my_start = e_lo + scan_l[t] - v;
    if (t < nn) {
        rp[n_lo + t] = my_start;
        dinv[n_lo + t] = (v > 0) ? rsqrtf((float)v) : 0.f;
    }
    if (b == NBUCKETS - 1 && t == 0) rp[N_NODES] = N_EDGES;
    __syncthreads();
    cnt_l[t] = my_start;
    __syncthreads();
    for (int e = e_lo + t; e < e_hi; e += 256) {
        unsigned p = tmp[e];
        int s = (int)(p & 0x1FFFFu);
        int tl = (int)(p >> 17);
        int pos = atomicAdd(&cnt_l[tl], 1);
        ssrc[pos] = s;
    }
}

// ----------------- MFMA fragment conventions -----------------
// A-frag (16x16x32): lane(q=lane>>4, cl=lane&15) holds A[row=cl][k=q*8+j].
// B-frag: lane holds B[k=q*8+j][col=cl] -> weights stored [col][k], 16B/lane.
// C/D: col=lane&15, row=q*4+reg (m89-verified).
// LDS A-tiles: granule(16B) index XOR'd with row bits to kill bank conflicts.

// dense1: 32-node tiles (grid 3125), float4 x loads, bf16-convert in staging.
// g output fp8x2; root output bf16x2 (accuracy: root is a direct additive term).
__global__ void __launch_bounds__(256) dense1_mfma(
        const float* __restrict__ x, const ushort* __restrict__ W1T,
        const float* __restrict__ dinv,
        ushort* __restrict__ g, unsigned* __restrict__ root) {
    __shared__ char xs[32 * 256];   // 8KB: 32 rows x 128 bf16 (K pad), swizzled
    int tid = threadIdx.x;
    int b0 = blockIdx.x * 32;
    // stage: 32 rows x 25 float4 (row bases 16B-aligned: 400 = 25*16)
    for (int i = tid; i < 32 * 25; i += 256) {
        int row = i / 25, f4 = i - row * 25;
        int grow = b0 + row;
        float4 v = make_float4(0.f, 0.f, 0.f, 0.f);
        if (grow < N_NODES) v = *(const float4*)(x + (size_t)grow * F_IN + f4 * 4);
        unsigned p0 = pack_bf2(v.x, v.y);
        unsigned p1 = pack_bf2(v.z, v.w);
        int pr = f4 * 2;                       // u32-pair index; pr and pr+1 share a granule
        int gr = (pr >> 2) ^ (row & 7);
        char* base = xs + row * 256 + (gr << 4) + (pr & 3) * 4;
        *(unsigned*)base = p0;
        *(unsigned*)(base + 4) = p1;
    }
    // zero-pad K cols 100..127 (u32 pairs 50..63)
    for (int i = tid; i < 32 * 14; i += 256) {
        int row = i / 14, pr = 50 + (i - row * 14);
        int gr = (pr >> 2) ^ (row & 7);
        *(unsigned*)(xs + row * 256 + (gr << 4) + (pr & 3) * 4) = 0;
    }
    __syncthreads();
    int lane = tid & 63;
    int w = __builtin_amdgcn_readfirstlane(tid >> 6);
    int q = lane >> 4, cl = lane & 15;
    int isWr = w >> 1;
    int colbase = (w & 1) * 32;
    v8s bfr[2][2][4];   // [stk][ntile][kstep]
    #pragma unroll
    for (int stk = 0; stk < 2; ++stk)
        #pragma unroll
        for (int nt = 0; nt < 2; ++nt)
            #pragma unroll
            for (int ks = 0; ks < 4; ++ks) {
                const ushort* p = W1T + ((size_t)(isWr * 2 + stk) * 64 + colbase + nt * 16 + cl) * 128
                                  + ks * 32 + q * 8;
                bfr[stk][nt][ks] = *(const v8s*)p;
            }
    #pragma unroll
    for (int mt = 0; mt < 2; ++mt) {
        v8s afr[4];
        #pragma unroll
        for (int ks = 0; ks < 4; ++ks) {
            int row = mt * 16 + cl;
            int gr = (ks * 4 + q) ^ (row & 7);
            afr[ks] = *(const v8s*)(xs + row * 256 + (gr << 4));
        }
        v4f acc[2][2];
        #pragma unroll
        for (int stk = 0; stk < 2; ++stk)
            #pragma unroll
            for (int nt = 0; nt < 2; ++nt) {
                v4f a = {0.f, 0.f, 0.f, 0.f};
                #pragma unroll
                for (int ks = 0; ks < 4; ++ks)
                    a = __builtin_amdgcn_mfma_f32_16x16x32_bf16(afr[ks], bfr[stk][nt][ks], a, 0, 0, 0);
                acc[stk][nt] = a;
            }
        #pragma unroll
        for (int nt = 0; nt < 2; ++nt)
            #pragma unroll
            for (int reg = 0; reg < 4; ++reg) {
                int node = b0 + mt * 16 + q * 4 + reg;
                if (node < N_NODES) {
                    int col = colbase + nt * 16 + cl;
                    if (isWr == 0) {
                        float dv = dinv[node];
                        g[(size_t)node * 64 + col] = pack_fp8x2(dv * acc[0][nt][reg], dv * acc[1][nt][reg]);
                    } else {
                        root[(size_t)node * 64 + col] = pack_bf2(acc[0][nt][reg], acc[1][nt][reg]);
                    }
                }
            }
    }
}

// dense_mid: hk0/hk1 planar bf16 -> fp8x2 g2 (x dinv). block = 64 nodes.
__global__ void __launch_bounds__(256) dense_mid_mfma(
        const ushort* __restrict__ hk0, const ushort* __restrict__ hk1,
        const ushort* __restrict__ WmT, const float* __restrict__ dinv,
        ushort* __restrict__ g2) {
    __shared__ char hs[2 * 64 * 128];   // 16KB: [stk][row][64 bf16], swizzled
    int tid = threadIdx.x;
    int b0 = blockIdx.x * 64;
    for (int i = tid; i < 1024; i += 256) {          // 2 tiles * 64 rows * 8 granules
        int stk = i >> 9, rem = i & 511, row = rem >> 3, gr = rem & 7;
        int grow = b0 + row;
        uint4 v = make_uint4(0, 0, 0, 0);
        const ushort* srcp = stk ? hk1 : hk0;
        if (grow < N_NODES) v = *(const uint4*)(srcp + (size_t)grow * 64 + gr * 8);
        *(uint4*)(hs + stk * 8192 + row * 128 + ((gr ^ (row & 7)) << 4)) = v;
    }
    __syncthreads();
    int lane = tid & 63;
    int w = __builtin_amdgcn_readfirstlane(tid >> 6);
    int q = lane >> 4, cl = lane & 15;
    v8s bfr[2][2];   // [stk][kstep]
    #pragma unroll
    for (int stk = 0; stk < 2; ++stk)
        #pragma unroll
        for (int ks = 0; ks < 2; ++ks)
            bfr[stk][ks] = *(const v8s*)(WmT + ((size_t)stk * 64 + w * 16 + cl) * 64 + ks * 32 + q * 8);
    #pragma unroll
    for (int mt = 0; mt < 4; ++mt) {
        v4f acc[2];
        #pragma unroll
        for (int stk = 0; stk < 2; ++stk) {
            v4f a = {0.f, 0.f, 0.f, 0.f};
            #pragma unroll
            for (int ks = 0; ks < 2; ++ks) {
                int row = mt * 16 + cl;
                int gr = (ks * 4 + q) ^ (row & 7);
                v8s af = *(const v8s*)(hs + stk * 8192 + row * 128 + (gr << 4));
                a = __builtin_amdgcn_mfma_f32_16x16x32_bf16(af, bfr[stk][ks], a, 0, 0, 0);
            }
            acc[stk] = a;
        }
        #pragma unroll
        for (int reg = 0; reg < 4; ++reg) {
            int node = b0 + mt * 16 + q * 4 + reg;
            if (node < N_NODES) {
                float dv = dinv[node];
                g2[(size_t)node * 64 + w * 16 + cl] = pack_fp8x2(dv * acc[0][reg], dv * acc[1][reg]);
            }
        }
    }
}

// dense_y2: yb planar bf16 -> h2 fp8x2 (x dinv) / root2 bf16x2. block = 64 nodes.
__global__ void __launch_bounds__(256) dense_y2_mfma(
        const ushort* __restrict__ yb, const ushort* __restrict__ W2T,
        const float* __restrict__ dinv,
        ushort* __restrict__ h2, unsigned* __restrict__ root2) {
    __shared__ char ys[64 * 128];   // 8KB: 64 rows x 64 bf16, swizzled
    int tid = threadIdx.x;
    int b0 = blockIdx.x * 64;
    for (int i = tid; i < 512; i += 256) {           // 64 rows * 8 granules
        int row = i >> 3, gr = i & 7;
        int grow = b0 + row;
        uint4 v = make_uint4(0, 0, 0, 0);
        if (grow < N_NODES) v = *(const uint4*)(yb + (size_t)grow * 64 + gr * 8);
        *(uint4*)(ys + row * 128 + ((gr ^ (row & 7)) << 4)) = v;
    }
    __syncthreads();
    int lane = tid & 63;
    int w = __builtin_amdgcn_readfirstlane(tid >> 6);
    int q = lane >> 4, cl = lane & 15;
    int isWr = w >> 1;
    int mbase = (w & 1) * 2;
    v8s bfr[2][2][2];   // [stk][ntile][kstep]
    #pragma unroll
    for (int stk = 0; stk < 2; ++stk)
        #pragma unroll
        for (int nt = 0; nt < 2; ++nt)
            #pragma unroll
            for (int ks = 0; ks < 2; ++ks)
                bfr[stk][nt][ks] = *(const v8s*)(W2T + ((size_t)(isWr * 2 + stk) * 32 + nt * 16 + cl) * 64
                                                 + ks * 32 + q * 8);
    #pragma unroll
    for (int mi = 0; mi < 2; ++mi) {
        int mt = mbase + mi;
        v8s afr[2];
        #pragma unroll
        for (int ks = 0; ks < 2; ++ks) {
            int row = mt * 16 + cl;
            int gr = (ks * 4 + q) ^ (row & 7);
            afr[ks] = *(const v8s*)(ys + row * 128 + (gr << 4));
        }
        v4f acc[2][2];
        #pragma unroll
        for (int stk = 0; stk < 2; ++stk)
            #pragma unroll
            for (int nt = 0; nt < 2; ++nt) {
                v4f a = {0.f, 0.f, 0.f, 0.f};
                #pragma unroll
                for (int ks = 0; ks < 2; ++ks)
                    a = __builtin_amdgcn_mfma_f32_16x16x32_bf16(afr[ks], bfr[stk][nt][ks], a, 0, 0, 0);
                acc[stk][nt] = a;
            }
        #pragma unroll
        for (int nt = 0; nt < 2; ++nt)
            #pragma unroll
            for (int reg = 0; reg < 4; ++reg) {
                int node = b0 + mt * 16 + q * 4 + reg;
                int col = nt * 16 + cl;
                if (node < N_NODES && col < C) {
                    if (isWr == 0) {
                        float dv = dinv[node];
                        h2[(size_t)node * C + col] = pack_fp8x2(dv * acc[0][nt][reg], dv * acc[1][nt][reg]);
                    } else {
                        root2[(size_t)node * C + col] = pack_bf2(acc[0][nt][reg], acc[1][nt][reg]);
                    }
                }
            }
    }
}

// dense_last: p18k0/p18k1 planar bf16 -> h3 fp8x2 (x dinv). block = 64 nodes.
__global__ void __launch_bounds__(256) dense_last_mfma(
        const ushort* __restrict__ ok0, const ushort* __restrict__ ok1,
        const ushort* __restrict__ W3T, const float* __restrict__ dinv,
        ushort* __restrict__ h3) {
    __shared__ char hs[2 * 64 * 64];   // 8KB: [stk][row][32 bf16], swizzle gr^(row&3)
    int tid = threadIdx.x;
    int b0 = blockIdx.x * 64;
    for (int i = tid; i < 2048; i += 256) ((unsigned*)hs)[i] = 0;
    __syncthreads();
    for (int i = tid; i < 4096; i += 256) {          // 2 stk * 64 rows * 32 cols
        int stk = i >> 11, row = (i >> 5) & 63, col = i & 31;
        int node = b0 + row;
        if (col < C && node < N_NODES) {
            ushort v = (stk ? ok1 : ok0)[(size_t)node * C + col];
            int gr = (col >> 3) ^ (row & 3);
            *(ushort*)(hs + stk * 4096 + row * 64 + (gr << 4) + (col & 7) * 2) = v;
        }
    }
    __syncthreads();
    int lane = tid & 63;
    int w = __builtin_amdgcn_readfirstlane(tid >> 6);
    int q = lane >> 4, cl = lane & 15;
    v8s bfr[2][2];   // [stk][ntile]
    #pragma unroll
    for (int stk = 0; stk < 2; ++stk)
        #pragma unroll
        for (int nt = 0; nt < 2; ++nt)
            bfr[stk][nt] = *(const v8s*)(W3T + ((size_t)stk * 32 + nt * 16 + cl) * 32 + q * 8);
    int row = w * 16 + cl;
    int gr = q ^ (row & 3);
    v8s af0 = *(const v8s*)(hs + row * 64 + (gr << 4));
    v8s af1 = *(const v8s*)(hs + 4096 + row * 64 + (gr << 4));
    v4f acc[2][2];
    #pragma unroll
    for (int nt = 0; nt < 2; ++nt) {
        acc[0][nt] = __builtin_amdgcn_mfma_f32_16x16x32_bf16(af0, bfr[0][nt], (v4f){0.f,0.f,0.f,0.f}, 0, 0, 0);
        acc[1][nt] = __builtin_amdgcn_mfma_f32_16x16x32_bf16(af1, bfr[1][nt], (v4f){0.f,0.f,0.f,0.f}, 0, 0, 0);
    }
    #pragma unroll
    for (int nt = 0; nt < 2; ++nt)
        #pragma unroll
        for (int reg = 0; reg < 4; ++reg) {
            int node = b0 + w * 16 + q * 4 + reg;
            int col = nt * 16 + cl;
            if (node < N_NODES && col < C) {
                float dv = dinv[node];
                h3[(size_t)node * C + col] = pack_fp8x2(dv * acc[0][nt][reg], dv * acc[1][nt][reg]);
            }
        }
}

// ----------------- propagation -----------------

// prop64: wave per node; DUAL-EDGE col-paired gathers. lane = (half, c32);
// each instruction loads a dword = cols {2c32, 2c32+1} of one edge row; halves
// process alternate edges via wave-uniform scalar pair + per-lane select.
template <int FINAL>
__global__ void __launch_bounds__(256) prop64_kernel(
        const ushort* __restrict__ g, const unsigned* __restrict__ root,
        const float* __restrict__ b, const float* __restrict__ dinv,
        const int* __restrict__ rp, const int* __restrict__ ssrc,
        ushort* __restrict__ ok0, ushort* __restrict__ ok1, ushort* __restrict__ yb) {
    int lane = threadIdx.x & 63;
    int wid = __builtin_amdgcn_readfirstlane((int)((blockIdx.x * 256 + threadIdx.x) >> 6));
    if (wid >= N_NODES) return;
    int e0 = rp[wid], e1 = rp[wid + 1];
    bool hi = lane >= 32;
    int c32 = lane & 31;                 // col pair: cols 2*c32, 2*c32+1
    const unsigned* g32 = (const unsigned*)g;   // dword view: node*32 + c32
    // hoisted epilogue operands (hide under gather loop)
    uint2 rtu = *(const uint2*)(root + (size_t)wid * H + 2 * c32);
    float dv = dinv[wid];
    float bA0 = b[2 * c32], bB0 = b[2 * c32 + 1];
    float bA1 = b[H + 2 * c32], bB1 = b[H + 2 * c32 + 1];
    float aA0 = 0.f, aA1 = 0.f, aB0 = 0.f, aB1 = 0.f;
    int e = e0;
    for (; e + 16 <= e1; e += 16) {      // 8 instructions x 2 edges each
        unsigned u[8];
        #pragma unroll
        for (int j = 0; j < 8; ++j) {
            int s0 = ssrc[e + 2 * j];        // scalar (e uniform)
            int s1 = ssrc[e + 2 * j + 1];    // scalar
            int srow = hi ? s1 : s0;
            u[j] = g32[(size_t)srow * 32 + c32];
        }
        #pragma unroll
        for (int j = 0; j < 8; ++j) {
            float2 vA = unpack_fp8x2((ushort)(u[j] & 0xFFFFu));
            float2 vB = unpack_fp8x2((ushort)(u[j] >> 16));
            aA0 += vA.x; aA1 += vA.y; aB0 += vB.x; aB1 += vB.y;
        }
    }
    for (; e + 2 <= e1; e += 2) {
        int s0 = ssrc[e];
        int s1 = ssrc[e + 1];
        int srow = hi ? s1 : s0;
        unsigned u = g32[(size_t)srow * 32 + c32];
        float2 vA = unpack_fp8x2((ushort)(u & 0xFFFFu));
        float2 vB = unpack_fp8x2((ushort)(u >> 16));
        aA0 += vA.x; aA1 += vA.y; aB0 += vB.x; aB1 += vB.y;
    }
    if (e < e1) {   // odd last edge: half 0 only
        int s0 = ssrc[e];
        unsigned u = g32[(size_t)s0 * 32 + c32];
        if (!hi) {
            float2 vA = unpack_fp8x2((ushort)(u & 0xFFFFu));
            float2 vB = unpack_fp8x2((ushort)(u >> 16));
            aA0 += vA.x; aA1 += vA.y; aB0 += vB.x; aB1 += vB.y;
        }
    }
    aA0 += __shfl_xor(aA0, 32, 64);
    aA1 += __shfl_xor(aA1, 32, 64);
    aB0 += __shfl_xor(aB0, 32, 64);
    aB1 += __shfl_xor(aB1, 32, 64);
    if (lane < 32) {
        float2 rtA = unpack_bf2(rtu.x);
        float2 rtB = unpack_bf2(rtu.y);
        float oA0 = fmaxf(fmaf(dv, aA0, rtA.x + bA0), 0.f);
        float oA1 = fmaxf(fmaf(dv, aA1, rtA.y + bA1), 0.f);
        float oB0 = fmaxf(fmaf(dv, aB0, rtB.x + bB0), 0.f);
        float oB1 = fmaxf(fmaf(dv, aB1, rtB.y + bB1), 0.f);
        size_t base = (size_t)wid * H + 2 * c32;
        if (FINAL) {
            *(unsigned*)(yb + base) = pack_bf2(0.5f * (oA0 + oA1), 0.5f * (oB0 + oB1));
        } else {
            *(unsigned*)(ok0 + base) = pack_bf2(oA0, oB0);
            *(unsigned*)(ok1 + base) = pack_bf2(oA1, oB1);
        }
    }
}

// prop18: wave per node; dual-edge via scalar pair + select (R16-proven).
template <int FINAL>
__global__ void __launch_bounds__(256) prop18_kernel(
        const ushort* __restrict__ g, const unsigned* __restrict__ root,
        const float* __restrict__ b, const float* __restrict__ dinv,
        const int* __restrict__ rp, const int* __restrict__ ssrc,
        ushort* __restrict__ ok0, ushort* __restrict__ ok1, float* __restrict__ outp) {
    int lane = threadIdx.x & 63;
    int wid = __builtin_amdgcn_readfirstlane((int)((blockIdx.x * 256 + threadIdx.x) >> 6));
    if (wid >= N_NODES) return;
    int e0 = rp[wid], e1 = rp[wid + 1];
    bool hi = lane >= 32;
    int c32 = lane & 31;
    bool actG = c32 < C;
    int c = actG ? c32 : 0;
    unsigned rtu = root[(size_t)wid * C + c];    // hoisted
    float dv = dinv[wid];
    float bl0 = b[c], bl1 = b[C + c];
    float a0 = 0.f, a1 = 0.f;
    int e = e0;
    for (; e + 16 <= e1; e += 16) {   // 8 instructions x 2 edges each
        ushort u[8];
        #pragma unroll
        for (int j = 0; j < 8; ++j) {
            int s0 = ssrc[e + 2 * j];        // scalar (e uniform)
            int s1 = ssrc[e + 2 * j + 1];    // scalar
            int srow = hi ? s1 : s0;
            u[j] = g[(size_t)srow * C + c];
        }
        if (actG) {
            #pragma unroll
            for (int j = 0; j < 8; ++j) { float2 v = unpack_fp8x2(u[j]); a0 += v.x; a1 += v.y; }
        }
    }
    for (; e + 2 <= e1; e += 2) {
        int s0 = ssrc[e];
        int s1 = ssrc[e + 1];
        int srow = hi ? s1 : s0;
        float2 v = unpack_fp8x2(g[(size_t)srow * C + c]);
        if (actG) { a0 += v.x; a1 += v.y; }
    }
    if (e < e1) {   // odd last edge: half 0 only
        int s0 = ssrc[e];
        float2 v = unpack_fp8x2(g[(size_t)s0 * C + c]);
        if (actG && !hi) { a0 += v.x; a1 += v.y; }
    }
    a0 += __shfl_xor(a0, 32, 64);
    a1 += __shfl_xor(a1, 32, 64);
    bool actO = lane < C;
    if (!FINAL) {
        if (actO) {
            float2 rt = unpack_bf2(rtu);
            float o0 = fmaxf(fmaf(dv, a0, rt.x + bl0), 0.f);
            float o1 = fmaxf(fmaf(dv, a1, rt.y + bl1), 0.f);
            ok0[(size_t)wid * C + c] = (ushort)bf16_rne(o0);
            ok1[(size_t)wid * C + c] = (ushort)bf16_rne(o1);
        }
    } else {
        float m = -INFINITY;
        if (actO) {
            float2 rt = unpack_bf2(rtu);
            float o0 = fmaxf(fmaf(dv, a0, rt.x + bl0), 0.f);
            float o1 = fmaxf(fmaf(dv, a1, rt.y + bl1), 0.f);
            m = 0.5f * (o0 + o1);
        }
        float mx = m;
        #pragma unroll
        for (int off = 16; off >= 1; off >>= 1) mx = fmaxf(mx, __shfl_xor(mx, off, 64));
        float ex = actO ? __expf(m - mx) : 0.f;
        float sum = ex;
        #pragma unroll
        for (int off = 16; off >= 1; off >>= 1) sum += __shfl_xor(sum, off, 64);
        if (actO) outp[(size_t)wid * C + c] = m - mx - logf(sum);
    }
}

// ----------------- launch -----------------

extern "C" void kernel_launch(void* const* d_in, const int* in_sizes, int n_in,
                              void* d_out, int out_size, void* d_ws, size_t ws_size,
                              hipStream_t stream) {
    const float* x        = (const float*)d_in[0];
    const int*   ei       = (const int*)d_in[1];
    const float* init_w1  = (const float*)d_in[2];
    const float* w1       = (const float*)d_in[3];
    const float* root_w1  = (const float*)d_in[4];
    const float* b1       = (const float*)d_in[5];
    const float* init_w2  = (const float*)d_in[6];
    const float* w2       = (const float*)d_in[7];
    const float* root_w2  = (const float*)d_in[8];
    const float* b2       = (const float*)d_in[9];
    const int* src = ei;
    const int* tgt = ei + N_EDGES;
    float* out = (float*)d_out;

    char* w = (char*)d_ws;
    size_t off = 0;
    auto alloc = [&](size_t bytes) -> char* {
        char* p = w + off;
        off += (bytes + 255) & ~(size_t)255;
        return p;
    };
    int*      rp    = (int*)alloc((size_t)(N_NODES + 1) * 4);
    float*    dinv  = (float*)alloc((size_t)N_NODES * 4);
    int*      bsum  = (int*)alloc(512 * 4);
    int*      hist  = (int*)alloc((size_t)NBUCKETS * NBLK * 4);
    int*      histx = (int*)alloc((size_t)NBUCKETS * NBLK * 4);
    unsigned* tmp   = (unsigned*)alloc((size_t)N_EDGES * 4);
    int*      ssrc  = (int*)alloc((size_t)N_EDGES * 4);
    ushort*   W1T   = (ushort*)alloc((size_t)4 * 64 * 128 * 2);
    ushort*   WmT   = (ushort*)alloc((size_t)2 * 64 * 64 * 2);
    ushort*   W2T   = (ushort*)alloc((size_t)4 * 32 * 64 * 2);
    ushort*   W3T   = (ushort*)alloc((size_t)2 * 32 * 32 * 2);
    ushort*   g1    = (ushort*)alloc((size_t)N_NODES * H * 2);    // 12.8 MB (fp8x2)
    unsigned* root1 = (unsigned*)alloc((size_t)N_NODES * H * 4);  // 25.6 MB (bf16x2)
    ushort*   hk0   = (ushort*)alloc((size_t)N_NODES * H * 2);    // 12.8 MB
    ushort*   hk1   = (ushort*)alloc((size_t)N_NODES * H * 2);    // 12.8 MB
    ushort*   g2    = (ushort*)alloc((size_t)N_NODES * H * 2);    // 12.8 MB (fp8x2)
    ushort*   yb    = (ushort*)alloc((size_t)N_NODES * H * 2);    // 12.8 MB
    ushort*   h2u   = (ushort*)alloc((size_t)N_NODES * C * 2);    // 3.6 MB (fp8x2)
    unsigned* root2u= (unsigned*)alloc((size_t)N_NODES * C * 4);  // 7.2 MB (bf16x2)
    ushort*   h3u   = (ushort*)alloc((size_t)N_NODES * C * 2);    // 3.6 MB (fp8x2)
    ushort*   p18k0 = (ushort*)g1;                           // [N*C] bf16 (g1 dead by then)
    ushort*   p18k1 = (ushort*)g1 + (size_t)N_NODES * C;

    int nbH = (NBUCKETS * NBLK + 255) / 256;         // 391

    // ---- CSR build (zero global atomics; scan3 folded into consumers) ----
    histA_kernel<<<NBLK, 256, 0, stream>>>(tgt, hist);
    scan1_kernel<<<nbH, 256, 0, stream>>>(hist, histx, bsum, NBUCKETS * NBLK);
    scan2p_prep_kernel<<<101, 512, 0, stream>>>(bsum, nbH,
                                                init_w1, root_w1, w1, init_w2, root_w2, w2,
                                                W1T, WmT, W2T, W3T);
    scatterC_kernel<<<NBLK, 256, 0, stream>>>(src, tgt, histx, bsum, tmp);
    bucketD2_kernel<<<NBUCKETS, 256, 0, stream>>>(tmp, histx, bsum, rp, dinv, ssrc);

    int g1blocks = (N_NODES + 31) / 32;         // 3125 (dense1 32-node tiles)
    int gblocks  = (N_NODES + 63) / 64;         // 1563
    int pgrid    = (N_NODES + 3) / 4;           // 25000 (wave per node)

    // ---- layer 1 ----
    dense1_mfma<<<g1blocks, 256, 0, stream>>>(x, W1T, dinv, g1, root1);
    prop64_kernel<0><<<pgrid, 256, 0, stream>>>(g1, root1, b1, dinv, rp, ssrc, hk0, hk1, nullptr);
    dense_mid_mfma<<<gblocks, 256, 0, stream>>>(hk0, hk1, WmT, dinv, g2);
    prop64_kernel<1><<<pgrid, 256, 0, stream>>>(g2, root1, b1, dinv, rp, ssrc, nullptr, nullptr, yb);

    // ---- layer 2 ----
    dense_y2_mfma<<<gblocks, 256, 0, stream>>>(yb, W2T, dinv, h2u, root2u);
    prop18_kernel<0><<<pgrid, 256, 0, stream>>>(h2u, root2u, b2, dinv, rp, ssrc, p18k0, p18k1, nullptr);
    dense_last_mfma<<<gblocks, 256, 0, stream>>>(p18k0, p18k1, W3T, dinv, h3u);
    prop18_kernel<1><<<pgrid, 256, 0, stream>>>(h3u, root2u, b2, dinv, rp, ssrc, nullptr, nullptr, out);
}